// Round 2
// baseline (285.108 us; speedup 1.0000x reference)
//
#include <hip/hip_runtime.h>

typedef unsigned short u16;
typedef __bf16 bf16x8 __attribute__((ext_vector_type(8)));
typedef float f32x4 __attribute__((ext_vector_type(4)));

#define LOG2E 1.44269504088896f

__device__ inline u16 f2b(float f) {
    unsigned u = __float_as_uint(f);
    u += 0x7fff + ((u >> 16) & 1);
    return (u16)(u >> 16);
}
__device__ inline float b2f(u16 u) { return __uint_as_float(((unsigned)u) << 16); }
__device__ inline f32x4 mfma_bf16(uint4 a, uint4 b, f32x4 c) {
    return __builtin_amdgcn_mfma_f32_16x16x32_bf16(
        __builtin_bit_cast(bf16x8, a), __builtin_bit_cast(bf16x8, b), c, 0, 0, 0);
}
// async global->LDS, 16 B per lane; LDS dest = wave-uniform base + lane*16
__device__ inline void ld16(const u16* g, u16* l) {
    __builtin_amdgcn_global_load_lds(
        (const __attribute__((address_space(1))) unsigned int*)g,
        (__attribute__((address_space(3))) unsigned int*)l, 16, 0, 0);
}
// 8x f32 -> packed bf16x8 via v_cvt_pk_bf16_f32 (RTNE, 2 elems/instr)
__device__ inline uint4 cvt8(float4 a, float4 b) {
    uint4 r;
    asm("v_cvt_pk_bf16_f32 %0, %1, %2" : "=v"(r.x) : "v"(a.x), "v"(a.y));
    asm("v_cvt_pk_bf16_f32 %0, %1, %2" : "=v"(r.y) : "v"(a.z), "v"(a.w));
    asm("v_cvt_pk_bf16_f32 %0, %1, %2" : "=v"(r.z) : "v"(b.x), "v"(b.y));
    asm("v_cvt_pk_bf16_f32 %0, %1, %2" : "=v"(r.w) : "v"(b.z), "v"(b.w));
    return r;
}

// ---------------------------------------------------------------------------
// Weight images, f32 -> bf16, granule-swizzled for bank-free LDS reads:
//   img[o][s*8+j] = W[c][o]  with  c = ((s ^ (o&7))<<3) | j
// (o = output col, c = contraction dim; 16B granule s lives at slot s^(o&7)).
//   WkT_img: W = Wqk[1] (c,d-out) ;  WvT_img: W = Wv ;  Wqb: plain [c][d].
// ---------------------------------------------------------------------------
__global__ __launch_bounds__(256) void prep_w(const float* __restrict__ Wqk,
                                              const float* __restrict__ Wv,
                                              u16* __restrict__ WkT,
                                              u16* __restrict__ WvT,
                                              u16* __restrict__ Wqb) {
    int idx = blockIdx.x * 256 + threadIdx.x;   // 0 .. 196607
    int which = idx >> 16;
    int i = (idx >> 8) & 255;   // output col o
    int j8 = idx & 255;
    if (which == 2) {
        Wqb[i * 256 + j8] = f2b(Wqk[i * 256 + j8]);   // plain [c][d]
        return;
    }
    int c = (((j8 >> 3) ^ (i & 7)) << 3) | (j8 & 7);
    if (which == 0)
        WkT[i * 256 + j8] = f2b(Wqk[65536 + c * 256 + i]);
    else
        WvT[i * 256 + j8] = f2b(Wv[c * 256 + i]);
}

// ---------------------------------------------------------------------------
// K / V projection, barrier-free steady state.
// grid 256 x 512thr (1 block/CU, 8 waves).  blockIdx&1 selects K or V matrix.
// Prologue: stage the FULL 128 KB weight image into LDS (one barrier).
// Then 4 slabs x 8 k-steps with NO barriers: A frags loaded global->VGPR
// (f32, 128B-contiguous per 4 q-lanes) + cvt_pk; B frags ds_read_b128 from
// the resident image (granule^(col&7) swizzle -> 2-way, free).
// Wave tile 32 rows x 128 cols (rt=2, ct=8) keeps L1 A-traffic < MFMA time.
// ---------------------------------------------------------------------------
__global__ __launch_bounds__(512, 2) void gemm_kv2(const float* __restrict__ A,
                                                   const u16* __restrict__ imgK,
                                                   const u16* __restrict__ imgV,
                                                   const float* __restrict__ biasK,
                                                   const float* __restrict__ biasV,
                                                   u16* __restrict__ KT,
                                                   u16* __restrict__ VT) {
    __shared__ __align__(16) u16 Bs[65536];   // 128 KiB (1 block/CU)
    const int t = threadIdx.x;
    const int mat = blockIdx.x & 1;
    const int grp = blockIdx.x >> 1;          // 0..127
    const int w = t >> 6, lane = t & 63, l15 = lane & 15, q = lane >> 4;
    const int cg = w >> 2, rg = w & 3;        // col-group 0..1, row-group 0..3
    const u16* img = mat ? imgV : imgK;
    const float* bias = mat ? biasV : biasK;
    u16* OUT = mat ? VT : KT;

#pragma unroll
    for (int s = 0; s < 16; ++s)
        ld16(img + (s * 512 + t) * 8, Bs + (s * 512 + w * 64) * 8);
    __syncthreads();   // the ONLY barrier

    const int e3 = l15 & 7;
    const int qx = q ^ (e3 & 3);
    const int ghi8 = (e3 & 4) * 8;
    const int bbase = (cg * 128 + l15) * 256 + qx * 8;

    for (int sl = 0; sl < 4; ++sl) {
        const long n0 = (long)grp * 512 + sl * 128;
        const int bb = (int)(n0 >> 13);
        const int nloc = (int)(n0 & 8191);
        const float* Ab = A + (n0 + rg * 32 + l15) * 256 + q * 8;

        f32x4 acc[2][8];
#pragma unroll
        for (int rt = 0; rt < 2; ++rt)
#pragma unroll
            for (int ct = 0; ct < 8; ++ct) acc[rt][ct] = f32x4{0.f, 0.f, 0.f, 0.f};

#pragma unroll
        for (int ks = 0; ks < 8; ++ks) {
            uint4 af[2];
#pragma unroll
            for (int rt = 0; rt < 2; ++rt) {
                const float* p = Ab + rt * 4096 + ks * 32;
                af[rt] = cvt8(((const float4*)p)[0], ((const float4*)p)[1]);
            }
            const int gofs = (ks * 32) ^ ghi8;
#pragma unroll
            for (int ct = 0; ct < 8; ++ct) {
                uint4 bf = *(const uint4*)(Bs + bbase + ct * 4096 + gofs);
                acc[0][ct] = mfma_bf16(af[0], bf, acc[0][ct]);
                acc[1][ct] = mfma_bf16(af[1], bf, acc[1][ct]);
            }
        }
        // direct C^T stores: OUT[(b,d)][n], 32B-contiguous per 4 q-lanes
#pragma unroll
        for (int ct = 0; ct < 8; ++ct) {
            const int col = cg * 128 + ct * 16 + l15;
            const float bv = bias[col];
#pragma unroll
            for (int rt = 0; rt < 2; ++rt) {
                ushort4 pk;
                pk.x = f2b(acc[rt][ct][0] + bv);
                pk.y = f2b(acc[rt][ct][1] + bv);
                pk.z = f2b(acc[rt][ct][2] + bv);
                pk.w = f2b(acc[rt][ct][3] + bv);
                *(ushort4*)(OUT + (((long)(bb * 256 + col)) << 13) + nloc +
                            rg * 32 + rt * 16 + q * 4) = pk;
            }
        }
    }
}

// ---------------------------------------------------------------------------
// Output GEMM, same barrier-free structure.  grid 256 x 512thr, 2 slabs.
// B = per-batch WfoldT image (swizzled by gemm_fold).  Out f32 row-major.
// ---------------------------------------------------------------------------
__global__ __launch_bounds__(512, 2) void gemm_out2(const float* __restrict__ A,
                                                    const u16* __restrict__ Wimg,
                                                    const float* __restrict__ outb,
                                                    float* __restrict__ C) {
    __shared__ __align__(16) u16 Bs[65536];
    const int t = threadIdx.x;
    const int w = t >> 6, lane = t & 63, l15 = lane & 15, q = lane >> 4;
    const int cg = w >> 2, rg = w & 3;
    const long r0 = (long)blockIdx.x * 256;
    const int bb = (int)(r0 >> 13);
    const u16* img = Wimg + (long)bb * 65536;

#pragma unroll
    for (int s = 0; s < 16; ++s)
        ld16(img + (s * 512 + t) * 8, Bs + (s * 512 + w * 64) * 8);
    __syncthreads();

    const int e3 = l15 & 7;
    const int qx = q ^ (e3 & 3);
    const int ghi8 = (e3 & 4) * 8;
    const int bbase = (cg * 128 + l15) * 256 + qx * 8;

    for (int sl = 0; sl < 2; ++sl) {
        const long n0 = r0 + sl * 128;
        const float* Ab = A + (n0 + rg * 32 + l15) * 256 + q * 8;

        f32x4 acc[2][8];
#pragma unroll
        for (int rt = 0; rt < 2; ++rt)
#pragma unroll
            for (int ct = 0; ct < 8; ++ct) acc[rt][ct] = f32x4{0.f, 0.f, 0.f, 0.f};

#pragma unroll
        for (int ks = 0; ks < 8; ++ks) {
            uint4 af[2];
#pragma unroll
            for (int rt = 0; rt < 2; ++rt) {
                const float* p = Ab + rt * 4096 + ks * 32;
                af[rt] = cvt8(((const float4*)p)[0], ((const float4*)p)[1]);
            }
            const int gofs = (ks * 32) ^ ghi8;
#pragma unroll
            for (int ct = 0; ct < 8; ++ct) {
                uint4 bf = *(const uint4*)(Bs + bbase + ct * 4096 + gofs);
                acc[0][ct] = mfma_bf16(af[0], bf, acc[0][ct]);
                acc[1][ct] = mfma_bf16(af[1], bf, acc[1][ct]);
            }
        }
#pragma unroll
        for (int ct = 0; ct < 8; ++ct) {
            const int col = cg * 128 + ct * 16 + l15;
            const float bv = outb[bb * 256 + col];
#pragma unroll
            for (int rt = 0; rt < 2; ++rt) {
                const long rbase = n0 + rg * 32 + rt * 16 + q * 4;
#pragma unroll
                for (int r = 0; r < 4; ++r)
                    C[(rbase + r) * 256 + col] = acc[rt][ct][r] + bv;
            }
        }
    }
}

// ---------------------------------------------------------------------------
// Split-K lam GEMM: ZERO LDS, ZERO barriers.  Both operands bf16 n-major ->
// MFMA frags load directly global->VGPR (1 dwordx4/frag, 64B per 4 q-lanes).
// grid (16 rowgroups, S chunks) x 512thr; wave = 64 (b,e)-rows x 64 d-cols.
// 256-deep independent k-chain per wave -> compiler pipelines loads freely.
// ---------------------------------------------------------------------------
__global__ __launch_bounds__(512, 2) void gemm_splitk2(const u16* __restrict__ VT,
                                                       const u16* __restrict__ PT,
                                                       float* __restrict__ lamP,
                                                       int chunk) {
    const int t = threadIdx.x;
    const int w = t >> 6, lane = t & 63, l15 = lane & 15, q = lane >> 4;
    const int rg = w & 1, cg = w >> 1;      // rows 128 = 2x64, cols 256 = 4x64
    const int r0 = blockIdx.x * 128;        // (b,e) rows
    const int s = blockIdx.y;
    const int bb = blockIdx.x >> 1;
    const long n0 = (long)s * chunk;

    const u16* Av = VT + (((long)(r0 + rg * 64 + l15)) << 13) + n0 + q * 8;
    const u16* Bp = PT + (((long)(bb * 256 + cg * 64 + l15)) << 13) + n0 + q * 8;

    f32x4 acc[4][4];
#pragma unroll
    for (int rt = 0; rt < 4; ++rt)
#pragma unroll
        for (int ct = 0; ct < 4; ++ct) acc[rt][ct] = f32x4{0.f, 0.f, 0.f, 0.f};

    const int nk = chunk >> 5;
#pragma unroll 4
    for (int ks = 0; ks < nk; ++ks) {
        uint4 af[4], bf[4];
#pragma unroll
        for (int i = 0; i < 4; ++i) {
            af[i] = *(const uint4*)(Av + (long)i * (16 * 8192) + ks * 32);
            bf[i] = *(const uint4*)(Bp + (long)i * (16 * 8192) + ks * 32);
        }
#pragma unroll
        for (int rt = 0; rt < 4; ++rt)
#pragma unroll
            for (int ct = 0; ct < 4; ++ct)
                acc[rt][ct] = mfma_bf16(af[rt], bf[ct], acc[rt][ct]);
    }

    float* outp = lamP + (long)s * 524288;
#pragma unroll
    for (int rt = 0; rt < 4; ++rt)
#pragma unroll
        for (int ct = 0; ct < 4; ++ct) {
            const int col = cg * 64 + ct * 16 + l15;
#pragma unroll
            for (int r = 0; r < 4; ++r)
                outp[(long)(r0 + rg * 64 + rt * 16 + q * 4 + r) * 256 + col] =
                    acc[rt][ct][r];
        }
}

// ---------------------------------------------------------------------------
// lamT[i] = sum_s lamP[s][i]   (coalesced float4)
// ---------------------------------------------------------------------------
__global__ __launch_bounds__(256) void reduce_lam(const float* __restrict__ lamP,
                                                  float* __restrict__ lamT, int S) {
    int i = blockIdx.x * 256 + threadIdx.x;  // float4 index, 131072 total
    float4 v = ((const float4*)lamP)[i];
    for (int s = 1; s < S; ++s) {
        float4 p = ((const float4*)(lamP + (long)s * 524288))[i];
        v.x += p.x; v.y += p.y; v.z += p.z; v.w += p.w;
    }
    ((float4*)lamT)[i] = v;
}

// ---------------------------------------------------------------------------
// Fold GEMM: WfoldT_img[b][e][swz(c)] = sum_d bnT[(b,e)][d] * Wqb[c][d].
// Output stored in the swizzled per-batch image layout gemm_out2 expects.
// ---------------------------------------------------------------------------
__global__ __launch_bounds__(256, 4) void gemm_fold(const u16* __restrict__ Abn,
                                                    const u16* __restrict__ Wqb,
                                                    u16* __restrict__ WfoldT) {
    __shared__ __align__(16) u16 lds[4096];  // As 64x32, Bs 64x32
    u16* As = lds;
    u16* Bs = lds + 2048;

    const int t = threadIdx.x;
    const int r0 = blockIdx.x * 64;
    const int c0 = blockIdx.y * 64;
    const int w = t >> 6, lane = t & 63, l15 = lane & 15, q = lane >> 4;

    f32x4 acc[4];
#pragma unroll
    for (int c = 0; c < 4; ++c) acc[c] = f32x4{0.f, 0.f, 0.f, 0.f};

    const int br = t >> 2;
    const int bk = (t & 3) * 8;

    for (int k0 = 0; k0 < 256; k0 += 32) {
        ld16(Abn + (long)(r0 + br) * 256 + k0 + bk, As + w * 512);
        ld16(Wqb + (long)(c0 + br) * 256 + k0 + bk, Bs + w * 512);
        __syncthreads();
        uint4 af = *(const uint4*)(As + (w * 16 + l15) * 32 + q * 8);
#pragma unroll
        for (int c = 0; c < 4; ++c) {
            uint4 bf = *(const uint4*)(Bs + (c * 16 + l15) * 32 + q * 8);
            acc[c] = mfma_bf16(af, bf, acc[c]);
        }
        __syncthreads();
    }

#pragma unroll
    for (int c = 0; c < 4; ++c) {
        int cidx = c0 + c * 16 + l15;
#pragma unroll
        for (int r = 0; r < 4; ++r) {
            int row = r0 + w * 16 + q * 4 + r;
            int e = row & 255, b2 = row >> 8;
            int swz = ((((cidx >> 3) ^ (e & 7)) << 3) | (cidx & 7));
            WfoldT[(long)b2 * 65536 + e * 256 + swz] = f2b(acc[c][r]);
        }
    }
}

// ---------------------------------------------------------------------------
// In-place softmax over each contiguous 8192-row of KT ([b*256+d][8192]).
// ---------------------------------------------------------------------------
__global__ __launch_bounds__(64) void softmax_rows(u16* __restrict__ KT) {
    const int row = blockIdx.x;
    const int lane = threadIdx.x;
    u16* p = KT + (long)row * 8192;

    uint4 buf[16];
#pragma unroll
    for (int i = 0; i < 16; ++i) buf[i] = *(const uint4*)(p + (i * 64 + lane) * 8);

    float m = -1e30f;
#pragma unroll
    for (int i = 0; i < 16; ++i) {
        const unsigned* u = (const unsigned*)&buf[i];
#pragma unroll
        for (int j = 0; j < 4; ++j) {
            m = fmaxf(m, fmaxf(b2f((u16)(u[j] & 0xffff)), b2f((u16)(u[j] >> 16))));
        }
    }
#pragma unroll
    for (int s = 32; s > 0; s >>= 1) m = fmaxf(m, __shfl_xor(m, s, 64));

    float sum = 0.f;
#pragma unroll
    for (int i = 0; i < 16; ++i) {
        const unsigned* u = (const unsigned*)&buf[i];
#pragma unroll
        for (int j = 0; j < 4; ++j) {
            sum += exp2f((b2f((u16)(u[j] & 0xffff)) - m) * LOG2E);
            sum += exp2f((b2f((u16)(u[j] >> 16)) - m) * LOG2E);
        }
    }
#pragma unroll
    for (int s = 32; s > 0; s >>= 1) sum += __shfl_xor(sum, s, 64);
    float rl = 1.0f / sum;

#pragma unroll
    for (int i = 0; i < 16; ++i) {
        unsigned* u = (unsigned*)&buf[i];
#pragma unroll
        for (int j = 0; j < 4; ++j) {
            float a = exp2f((b2f((u16)(u[j] & 0xffff)) - m) * LOG2E) * rl;
            float b = exp2f((b2f((u16)(u[j] >> 16)) - m) * LOG2E) * rl;
            u[j] = (unsigned)f2b(a) | ((unsigned)f2b(b) << 16);
        }
        *(uint4*)(p + (i * 64 + lane) * 8) = buf[i];
    }
}

// ---------------------------------------------------------------------------
// BatchNorm over lam^T[(b*256+e)][d]: stats per d over 2048 (b,e) values.
// ---------------------------------------------------------------------------
__global__ __launch_bounds__(256) void bn_kernel(const float* __restrict__ lamT,
                                                 const float* __restrict__ gamma,
                                                 const float* __restrict__ beta,
                                                 u16* __restrict__ bnT) {
    const int d = blockIdx.x;
    const int t = threadIdx.x;
    float vals[8];
    float s = 0.f, ss = 0.f;
#pragma unroll
    for (int i = 0; i < 8; ++i) {
        float v = lamT[(long)(i * 256 + t) * 256 + d];
        vals[i] = v;
        s += v;
        ss += v * v;
    }
#pragma unroll
    for (int sh = 32; sh > 0; sh >>= 1) {
        s += __shfl_xor(s, sh, 64);
        ss += __shfl_xor(ss, sh, 64);
    }
    __shared__ float red[8];
    int w = t >> 6;
    if ((t & 63) == 0) {
        red[w] = s;
        red[w + 4] = ss;
    }
    __syncthreads();
    s = red[0] + red[1] + red[2] + red[3];
    ss = red[4] + red[5] + red[6] + red[7];
    float mean = s * (1.f / 2048.f);
    float var = ss * (1.f / 2048.f) - mean * mean;
    float scale = gamma[d] * rsqrtf(var + 1e-5f);
    float shift = beta[d] - mean * scale;
#pragma unroll
    for (int i = 0; i < 8; ++i)
        bnT[(long)(i * 256 + t) * 256 + d] = f2b(vals[i] * scale + shift);
}

// ---------------------------------------------------------------------------
// outb[b][e] = sum_d bq[d] * bnT[b][e][d]   (folded query bias)
// ---------------------------------------------------------------------------
__global__ __launch_bounds__(256) void outb_kernel(const float* __restrict__ bq,
                                                   const u16* __restrict__ bnT,
                                                   float* __restrict__ outb) {
    int b = blockIdx.x, e = threadIdx.x;
    const u16* rowp = bnT + ((long)b * 256 + e) * 256;
    float s = 0.f;
    for (int dd = 0; dd < 256; ++dd) s += bq[dd] * b2f(rowp[dd]);
    outb[b * 256 + e] = s;
}

// ---------------------------------------------------------------------------
extern "C" void kernel_launch(void* const* d_in, const int* in_sizes, int n_in,
                              void* d_out, int out_size, void* d_ws, size_t ws_size,
                              hipStream_t stream) {
    const float* feat = (const float*)d_in[0];   // (8,8192,256) f32
    const float* W_qk = (const float*)d_in[1];   // (2,256,256) f32
    const float* b_qk = (const float*)d_in[2];   // (2,256) f32
    const float* W_v = (const float*)d_in[3];    // (256,256) f32
    const float* b_v = (const float*)d_in[4];    // (256,) f32
    const float* gamma = (const float*)d_in[5];  // (256,) f32
    const float* beta = (const float*)d_in[6];   // (256,) f32
    float* out = (float*)d_out;                  // (8,8192,256) f32

    char* ws = (char*)d_ws;
    u16* KT = (u16*)(ws);                        // [b][d][n] 33,554,432 B (P after softmax)
    u16* VT = (u16*)(ws + 33554432);             // [b][e][n] 33,554,432 B
    u16* WkT = (u16*)(ws + 67108864);            // 131072 B (swizzled image)
    u16* WvT = (u16*)(ws + 67239936);            // 131072 B (swizzled image)
    u16* Wqb = (u16*)(ws + 67371008);            // 131072 B (plain)
    const size_t base = 67502080;
    float* lamP = (float*)(ws + base);           // S * 2,097,152 B
    size_t avail = (ws_size > base) ? ws_size - base : 0;
    int S = (avail >= 16u * 2097152u) ? 16
          : (avail >= 8u * 2097152u) ? 8
          : (avail >= 4u * 2097152u) ? 4 : 2;
    // post-split-K buffers alias the dead P region (KT):
    float* lamT = (float*)ws;                    // 2,097,152 B
    u16* bnT = (u16*)(ws + 2097152);             // 1,048,576 B
    u16* WfoldT = (u16*)(ws + 3145728);          // 1,048,576 B (swizzled images)
    float* outb = (float*)(ws + 4194304);        // 8,192 B

    // 1. weight prep (swizzled images)
    prep_w<<<768, 256, 0, stream>>>(W_qk, W_v, WkT, WvT, Wqb);
    // 2. K^T / V^T projection, barrier-free (1 block/CU, weights resident in LDS)
    gemm_kv2<<<256, 512, 0, stream>>>(feat, WkT, WvT, b_qk + 256, b_v, KT, VT);
    // 3. in-place softmax over n -> P^T
    softmax_rows<<<2048, 64, 0, stream>>>(KT);
    // 4. split-K lam partials (no LDS, no barriers) + reduce
    gemm_splitk2<<<dim3(16, S), 512, 0, stream>>>(VT, KT, lamP, 8192 / S);
    reduce_lam<<<512, 256, 0, stream>>>(lamP, lamT, S);
    // 5. BN -> bn^T bf16
    bn_kernel<<<256, 256, 0, stream>>>(lamT, gamma, beta, bnT);
    // 6. folded query bias
    outb_kernel<<<8, 256, 0, stream>>>(b_qk, bnT, outb);
    // 7. Wfold^T images = bn^T @ Wq^T (swizzled store)
    gemm_fold<<<dim3(32, 4), 256, 0, stream>>>(bnT, Wqb, WfoldT);
    // 8. out = X @ Wfold (+outb), barrier-free
    gemm_out2<<<256, 512, 0, stream>>>(feat, WfoldT, outb, out);
}

// Round 3
// 272.822 us; speedup vs baseline: 1.0450x; 1.0450x over previous
//
#include <hip/hip_runtime.h>

typedef unsigned short u16;
typedef __bf16 bf16x8 __attribute__((ext_vector_type(8)));
typedef float f32x4 __attribute__((ext_vector_type(4)));

#define LOG2E 1.44269504088896f

__device__ inline u16 f2b(float f) {
    unsigned u = __float_as_uint(f);
    u += 0x7fff + ((u >> 16) & 1);
    return (u16)(u >> 16);
}
__device__ inline float b2f(u16 u) { return __uint_as_float(((unsigned)u) << 16); }
__device__ inline unsigned pk2(float a, float b) {
    return (unsigned)f2b(a) | ((unsigned)f2b(b) << 16);
}
__device__ inline uint4 pack8(float4 a, float4 b) {
    return uint4{pk2(a.x, a.y), pk2(a.z, a.w), pk2(b.x, b.y), pk2(b.z, b.w)};
}
__device__ inline f32x4 mfma_bf16(uint4 a, uint4 b, f32x4 c) {
    return __builtin_amdgcn_mfma_f32_16x16x32_bf16(
        __builtin_bit_cast(bf16x8, a), __builtin_bit_cast(bf16x8, b), c, 0, 0, 0);
}
// async global->LDS, 16 B per lane; LDS dest = wave-uniform base + lane*16
__device__ inline void ld16(const u16* g, u16* l) {
    __builtin_amdgcn_global_load_lds(
        (const __attribute__((address_space(1))) unsigned int*)g,
        (__attribute__((address_space(3))) unsigned int*)l, 16, 0, 0);
}
// P = exp2(k*LOG2E - c) applied to a bf16x8 fragment (nc = -c), repacked bf16.
__device__ inline uint4 expfrag(uint4 v, float nc) {
    float e[8];
#pragma unroll
    for (int i = 0; i < 4; ++i) {
        unsigned u = ((const unsigned*)&v)[i];
        e[2 * i] = exp2f(fmaf(b2f((u16)(u & 0xffff)), LOG2E, nc));
        e[2 * i + 1] = exp2f(fmaf(b2f((u16)(u >> 16)), LOG2E, nc));
    }
    uint4 r;
    asm("v_cvt_pk_bf16_f32 %0, %1, %2" : "=v"(r.x) : "v"(e[0]), "v"(e[1]));
    asm("v_cvt_pk_bf16_f32 %0, %1, %2" : "=v"(r.y) : "v"(e[2]), "v"(e[3]));
    asm("v_cvt_pk_bf16_f32 %0, %1, %2" : "=v"(r.z) : "v"(e[4]), "v"(e[5]));
    asm("v_cvt_pk_bf16_f32 %0, %1, %2" : "=v"(r.w) : "v"(e[6]), "v"(e[7]));
    return r;
}

// Tiled intermediate layout: KT/VT [b][nt(256)][d(256)][n-in-tile(32)] bf16.
// Tile = 16 KB contiguous (d-major inside) -> streaming HBM writes from
// gemm_kv (2 tiles/block) and streaming 8-KB slab reads in gemm_splitk.

// ---------------------------------------------------------------------------
// Weight prep (f32 -> bf16), plain layouts (r1):
//   WkT[e][d] = Wqk[1][d][e],  WvT[e][d] = Wv[d][e],  Wqb[c][d] = Wqk[0][c][d]
// ---------------------------------------------------------------------------
__global__ __launch_bounds__(256) void prep_w(const float* __restrict__ Wqk,
                                              const float* __restrict__ Wv,
                                              u16* __restrict__ WkT,
                                              u16* __restrict__ WvT,
                                              u16* __restrict__ Wqb) {
    int idx = blockIdx.x * 256 + threadIdx.x;   // 0 .. 196607
    int which = idx >> 16;
    int i = (idx >> 8) & 255;
    int j = idx & 255;
    if (which == 0)
        WkT[i * 256 + j] = f2b(Wqk[65536 + j * 256 + i]);
    else if (which == 1)
        WvT[i * 256 + j] = f2b(Wv[j * 256 + i]);
    else
        Wqb[i * 256 + j] = f2b(Wqk[i * 256 + j]);
}

// ---------------------------------------------------------------------------
// Fused K+V projection (r1 body: dbuf + swizzle + 4x4/wave tiling), with
// TILED epilogue stores + fused per-block online-softmax partials for K.
// ---------------------------------------------------------------------------
__global__ __launch_bounds__(256, 2) void gemm_kv(const float* __restrict__ A,
                                                  const u16* __restrict__ BtK,
                                                  const u16* __restrict__ BtV,
                                                  const float* __restrict__ biasK,
                                                  const float* __restrict__ biasV,
                                                  u16* __restrict__ KT,
                                                  u16* __restrict__ VT,
                                                  float* __restrict__ partial) {
    __shared__ __align__(16) u16 lds[36864];

    const int t = threadIdx.x;
    const int r0 = blockIdx.x * 64;
    const int w = t >> 6, lane = t & 63, l15 = lane & 15, q = lane >> 4;
    const int sq = ((lane & 3) ^ ((lane >> 3) & 3)) * 8;  // staging src swizzle
    const int qs = (q ^ ((l15 >> 1) & 3)) * 8;            // frag read swizzle
    const int awoff = (t >> 2) * 32 + sq;                 // swizzled A ds_write
    const int brr = t >> 2;

    f32x4 accK[4][4], accV[4][4];
#pragma unroll
    for (int rt = 0; rt < 4; ++rt)
#pragma unroll
        for (int ct = 0; ct < 4; ++ct) {
            accK[rt][ct] = f32x4{0.f, 0.f, 0.f, 0.f};
            accV[rt][ct] = f32x4{0.f, 0.f, 0.f, 0.f};
        }

    const float* Arow = A + (long)(r0 + brr) * 256 + (t & 3) * 8;
    float4 p0 = ((const float4*)Arow)[0], p1 = ((const float4*)Arow)[1];
    float4 c0_ = *(const float4*)(Arow + 32), c1_ = *(const float4*)(Arow + 36);
    float4 d0_ = *(const float4*)(Arow + 64), d1_ = *(const float4*)(Arow + 68);

    // prologue: stage k0=0 into buffer 0
    {
        u16* dK = lds + 4096 + w * 512;
#pragma unroll
        for (int j = 0; j < 4; ++j) {
            int br = j * 64 + brr;
            ld16(BtK + br * 256 + sq, dK + j * 2048);
            ld16(BtV + br * 256 + sq, dK + 8192 + j * 2048);
        }
    }
    *(uint4*)(lds + awoff) = pack8(p0, p1);
    __syncthreads();

#pragma unroll
    for (int t8 = 0; t8 < 8; ++t8) {
        const int cur = t8 & 1;
        if (t8 < 7) {  // stage next k-slab into the other buffer (async)
            const int k0 = (t8 + 1) * 32;
            u16* dK = lds + 4096 + (cur ^ 1) * 16384 + w * 512;
#pragma unroll
            for (int j = 0; j < 4; ++j) {
                int br = j * 64 + brr;
                ld16(BtK + br * 256 + k0 + sq, dK + j * 2048);
                ld16(BtV + br * 256 + k0 + sq, dK + 8192 + j * 2048);
            }
            *(uint4*)(lds + (cur ^ 1) * 2048 + awoff) = pack8(c0_, c1_);
            c0_ = d0_; c1_ = d1_;
            if (t8 < 5) {
                d0_ = *(const float4*)(Arow + (t8 + 3) * 32);
                d1_ = *(const float4*)(Arow + (t8 + 3) * 32 + 4);
            }
        }
        const u16* Asc = lds + cur * 2048;
        const u16* Bc = lds + 4096 + cur * 16384;
        uint4 af[4];
#pragma unroll
        for (int rt = 0; rt < 4; ++rt)
            af[rt] = *(const uint4*)(Asc + (rt * 16 + l15) * 32 + qs);
#pragma unroll
        for (int ct = 0; ct < 4; ++ct) {
            const int bo = (w * 64 + ct * 16 + l15) * 32 + qs;
            uint4 bK = *(const uint4*)(Bc + bo);
            uint4 bV = *(const uint4*)(Bc + 8192 + bo);
#pragma unroll
            for (int rt = 0; rt < 4; ++rt) {
                accK[rt][ct] = mfma_bf16(af[rt], bK, accK[rt][ct]);
                accV[rt][ct] = mfma_bf16(af[rt], bV, accV[rt][ct]);
            }
        }
        __syncthreads();
    }

    // epilogue: bias + LDS transpose + TILED stores; pass 0 also emits
    // per-(b,d) online-softmax partials (m,s) over this block's 64 n.
    const int bb = r0 >> 13;
    const int nt0 = (r0 & 8191) >> 5;      // first of 2 tiles
    const int nch = nt0 >> 1;              // 0..127 partial slot
    u16* Ct = lds;
#pragma unroll
    for (int pass = 0; pass < 2; ++pass) {
        const f32x4(*acc)[4] = pass ? accV : accK;
        const float* bias = pass ? biasV : biasK;
        u16* CT = pass ? VT : KT;
#pragma unroll
        for (int ct = 0; ct < 4; ++ct) {
            const int col = w * 64 + ct * 16 + l15;
            const float bv = bias[col];
            ushort4 pks[4];
#pragma unroll
            for (int rt = 0; rt < 4; ++rt) {
                ushort4 pk;
                pk.x = f2b(acc[rt][ct][0] + bv);
                pk.y = f2b(acc[rt][ct][1] + bv);
                pk.z = f2b(acc[rt][ct][2] + bv);
                pk.w = f2b(acc[rt][ct][3] + bv);
                pks[rt] = pk;
                *(ushort4*)&Ct[col * 72 + rt * 16 + q * 4] = pk;
            }
            if (pass == 0) {
                float zm = -1e30f;
#pragma unroll
                for (int rt = 0; rt < 4; ++rt)
                    zm = fmaxf(zm,
                               fmaxf(fmaxf(b2f(pks[rt].x), b2f(pks[rt].y)),
                                     fmaxf(b2f(pks[rt].z), b2f(pks[rt].w))));
                zm = fmaxf(zm, __shfl_xor(zm, 16, 64));
                zm = fmaxf(zm, __shfl_xor(zm, 32, 64));
                zm *= LOG2E;   // z-space max
                float zs = 0.f;
#pragma unroll
                for (int rt = 0; rt < 4; ++rt) {
                    zs += exp2f(fmaf(b2f(pks[rt].x), LOG2E, -zm));
                    zs += exp2f(fmaf(b2f(pks[rt].y), LOG2E, -zm));
                    zs += exp2f(fmaf(b2f(pks[rt].z), LOG2E, -zm));
                    zs += exp2f(fmaf(b2f(pks[rt].w), LOG2E, -zm));
                }
                zs += __shfl_xor(zs, 16, 64);
                zs += __shfl_xor(zs, 32, 64);
                if (q == 0) {
                    float* pp =
                        partial + (((long)(bb * 128 + nch)) * 256 + col) * 2;
                    pp[0] = zm;
                    pp[1] = zs;
                }
            }
        }
        __syncthreads();
        {   // tiled store: CT[((bb*256 + nt0+j2)*256 + d)*32 + ...]
            const long tb = (((long)(bb * 256 + nt0)) * 256 + t) * 32;
#pragma unroll
            for (int j2 = 0; j2 < 2; ++j2)
#pragma unroll
                for (int g = 0; g < 4; ++g)
                    *(uint4*)(CT + tb + j2 * 8192 + g * 8) =
                        *(const uint4*)&Ct[t * 72 + j2 * 32 + g * 8];
        }
        __syncthreads();
    }
}

// ---------------------------------------------------------------------------
// Combine per-chunk softmax partials: c[b][d] = M + log2(sum_i s_i*2^(m_i-M)).
// ---------------------------------------------------------------------------
__global__ __launch_bounds__(256) void stats2(const float* __restrict__ partial,
                                              float* __restrict__ ctab) {
    const int b = blockIdx.x, d = threadIdx.x;
    float M = -1e30f;
    for (int i = 0; i < 128; ++i)
        M = fmaxf(M, partial[(((long)(b * 128 + i)) * 256 + d) * 2]);
    float S = 0.f;
    for (int i = 0; i < 128; ++i) {
        const float* pp = partial + (((long)(b * 128 + i)) * 256 + d) * 2;
        S += pp[1] * exp2f(pp[0] - M);
    }
    ctab[b * 256 + d] = M + log2f(S);
}

// ---------------------------------------------------------------------------
// Output GEMM (r1 verbatim): out[b][n][e] = sum_c X[n][c]*WfoldT[(b,e)][c]+outb.
// ---------------------------------------------------------------------------
__global__ __launch_bounds__(256, 3) void gemm_out(const float* __restrict__ A,
                                                   const u16* __restrict__ WfoldT,
                                                   const float* __restrict__ outb,
                                                   float* __restrict__ C) {
    __shared__ __align__(16) u16 lds[20480];
    const int t = threadIdx.x;
    const int r0 = blockIdx.x * 64;
    const int bb = r0 >> 13;
    const int w = t >> 6, lane = t & 63, l15 = lane & 15, q = lane >> 4;
    const int sq = ((lane & 3) ^ ((lane >> 3) & 3)) * 8;
    const int qs = (q ^ ((l15 >> 1) & 3)) * 8;
    const int awoff = (t >> 2) * 32 + sq;
    const int brr = t >> 2;
    const u16* Bt = WfoldT + (long)bb * 65536;

    f32x4 acc[4][4];
#pragma unroll
    for (int rt = 0; rt < 4; ++rt)
#pragma unroll
        for (int ct = 0; ct < 4; ++ct) acc[rt][ct] = f32x4{0.f, 0.f, 0.f, 0.f};

    const float* Arow = A + (long)(r0 + brr) * 256 + (t & 3) * 8;
    float4 p0 = ((const float4*)Arow)[0], p1 = ((const float4*)Arow)[1];
    float4 c0_ = *(const float4*)(Arow + 32), c1_ = *(const float4*)(Arow + 36);
    float4 d0_ = *(const float4*)(Arow + 64), d1_ = *(const float4*)(Arow + 68);

    {
        u16* dB = lds + 4096 + w * 512;
#pragma unroll
        for (int j = 0; j < 4; ++j)
            ld16(Bt + (j * 64 + brr) * 256 + sq, dB + j * 2048);
    }
    *(uint4*)(lds + awoff) = pack8(p0, p1);
    __syncthreads();

#pragma unroll
    for (int t8 = 0; t8 < 8; ++t8) {
        const int cur = t8 & 1;
        if (t8 < 7) {
            const int k0 = (t8 + 1) * 32;
            u16* dB = lds + 4096 + (cur ^ 1) * 8192 + w * 512;
#pragma unroll
            for (int j = 0; j < 4; ++j)
                ld16(Bt + (j * 64 + brr) * 256 + k0 + sq, dB + j * 2048);
            *(uint4*)(lds + (cur ^ 1) * 2048 + awoff) = pack8(c0_, c1_);
            c0_ = d0_; c1_ = d1_;
            if (t8 < 5) {
                d0_ = *(const float4*)(Arow + (t8 + 3) * 32);
                d1_ = *(const float4*)(Arow + (t8 + 3) * 32 + 4);
            }
        }
        const u16* Asc = lds + cur * 2048;
        const u16* Bc = lds + 4096 + cur * 8192;
        uint4 af[4];
#pragma unroll
        for (int rt = 0; rt < 4; ++rt)
            af[rt] = *(const uint4*)(Asc + (rt * 16 + l15) * 32 + qs);
#pragma unroll
        for (int ct = 0; ct < 4; ++ct) {
            uint4 bf = *(const uint4*)(Bc + (w * 64 + ct * 16 + l15) * 32 + qs);
#pragma unroll
            for (int rt = 0; rt < 4; ++rt)
                acc[rt][ct] = mfma_bf16(af[rt], bf, acc[rt][ct]);
        }
        __syncthreads();
    }

#pragma unroll
    for (int ct = 0; ct < 4; ++ct) {
        const int col = w * 64 + ct * 16 + l15;
        const float bv = outb[bb * 256 + col];
#pragma unroll
        for (int rt = 0; rt < 4; ++rt) {
            const long rbase = r0 + rt * 16 + q * 4;
#pragma unroll
            for (int r = 0; r < 4; ++r)
                C[(rbase + r) * 256 + col] = acc[rt][ct][r] + bv;
        }
    }
}

// ---------------------------------------------------------------------------
// Split-K lam GEMM over TILED VT/KT with on-the-fly P = exp2(k*LOG2E - c).
// r1 structure (dbuf + swizzle, 8x2 frags/wave), streaming 8-KB slab loads.
// ---------------------------------------------------------------------------
__global__ __launch_bounds__(256, 2) void gemm_splitk(const u16* __restrict__ VT,
                                                      const u16* __restrict__ KT,
                                                      const float* __restrict__ ctab,
                                                      float* __restrict__ lamP,
                                                      int chunk) {
    __shared__ __align__(16) u16 lds[16384];
    const int t = threadIdx.x;
    const int r0 = blockIdx.x * 128;   // (b,e) rows
    const int c0 = blockIdx.y * 128;   // d cols
    const int s = blockIdx.z;
    const int bA = r0 >> 8, e0 = r0 & 255;
    const int w = t >> 6, lane = t & 63, l15 = lane & 15, q = lane >> 4;
    const int sq = ((lane & 3) ^ ((lane >> 3) & 3)) * 8;
    const int qs = (q ^ ((l15 >> 1) & 3)) * 8;
    const int brr = t >> 2;

    const int nt_base = (int)(((long)s * chunk) >> 5);
    const u16* Abase = VT + (((long)bA * 256 + nt_base) * 256 + e0) * 32;
    const u16* Bbase = KT + (((long)bA * 256 + nt_base) * 256 + c0) * 32;

    const float nc0 = -ctab[bA * 256 + c0 + w * 32 + l15];
    const float nc1 = -ctab[bA * 256 + c0 + w * 32 + 16 + l15];

    f32x4 acc[8][2];
#pragma unroll
    for (int rt = 0; rt < 8; ++rt) {
        acc[rt][0] = f32x4{0.f, 0.f, 0.f, 0.f};
        acc[rt][1] = f32x4{0.f, 0.f, 0.f, 0.f};
    }

    {
        u16* dA = lds + w * 512;
#pragma unroll
        for (int j = 0; j < 2; ++j) {
            int br = j * 64 + brr;
            ld16(Abase + br * 32 + sq, dA + j * 2048);
            ld16(Bbase + br * 32 + sq, dA + 4096 + j * 2048);
        }
    }
    __syncthreads();

    const int nk = chunk >> 5;
    for (int ks = 0; ks < nk; ++ks) {
        const int cur = ks & 1;
        if (ks + 1 < nk) {
            const long toff = (long)(ks + 1) * 8192;   // next tile (16 KB)
            u16* dA = lds + (cur ^ 1) * 8192 + w * 512;
#pragma unroll
            for (int j = 0; j < 2; ++j) {
                int br = j * 64 + brr;
                ld16(Abase + toff + br * 32 + sq, dA + j * 2048);
                ld16(Bbase + toff + br * 32 + sq, dA + 4096 + j * 2048);
            }
        }
        const u16* Asc = lds + cur * 8192;
        const u16* Bsc = Asc + 4096;
        const int bo = (w * 32 + l15) * 32 + qs;
        uint4 bf0 = expfrag(*(const uint4*)(Bsc + bo), nc0);
        uint4 bf1 = expfrag(*(const uint4*)(Bsc + 512 + bo), nc1);
#pragma unroll
        for (int rt = 0; rt < 8; ++rt) {
            uint4 af = *(const uint4*)(Asc + (rt * 16 + l15) * 32 + qs);
            acc[rt][0] = mfma_bf16(af, bf0, acc[rt][0]);
            acc[rt][1] = mfma_bf16(af, bf1, acc[rt][1]);
        }
        __syncthreads();
    }

    float* outp = lamP + (long)s * 524288;
#pragma unroll
    for (int rt = 0; rt < 8; ++rt)
#pragma unroll
        for (int ct = 0; ct < 2; ++ct) {
            const int col = c0 + w * 32 + ct * 16 + l15;
#pragma unroll
            for (int r = 0; r < 4; ++r)
                outp[(long)(r0 + rt * 16 + q * 4 + r) * 256 + col] =
                    acc[rt][ct][r];
        }
}

// ---------------------------------------------------------------------------
// lamT[i] = sum_s lamP[s][i]   (coalesced float4)
// ---------------------------------------------------------------------------
__global__ __launch_bounds__(256) void reduce_lam(const float* __restrict__ lamP,
                                                  float* __restrict__ lamT, int S) {
    int i = blockIdx.x * 256 + threadIdx.x;  // float4 index, 131072 total
    float4 v = ((const float4*)lamP)[i];
    for (int s = 1; s < S; ++s) {
        float4 p = ((const float4*)(lamP + (long)s * 524288))[i];
        v.x += p.x; v.y += p.y; v.z += p.z; v.w += p.w;
    }
    ((float4*)lamT)[i] = v;
}

// ---------------------------------------------------------------------------
// Fold GEMM (r1 verbatim): WfoldT[(b,e)][c] = sum_d bnT[(b,e)][d] * Wqb[c][d].
// ---------------------------------------------------------------------------
__global__ __launch_bounds__(256, 4) void gemm_fold(const u16* __restrict__ Abn,
                                                    const u16* __restrict__ Wqb,
                                                    u16* __restrict__ WfoldT) {
    __shared__ __align__(16) u16 lds[4096];  // As 64x32, Bs 64x32
    u16* As = lds;
    u16* Bs = lds + 2048;

    const int t = threadIdx.x;
    const int r0 = blockIdx.x * 64;
    const int c0 = blockIdx.y * 64;
    const int w = t >> 6, lane = t & 63, l15 = lane & 15, q = lane >> 4;

    f32x4 acc[4];
#pragma unroll
    for (int c = 0; c < 4; ++c) acc[c] = f32x4{0.f, 0.f, 0.f, 0.f};

    const int br = t >> 2;
    const int bk = (t & 3) * 8;

    for (int k0 = 0; k0 < 256; k0 += 32) {
        ld16(Abn + (long)(r0 + br) * 256 + k0 + bk, As + w * 512);
        ld16(Wqb + (long)(c0 + br) * 256 + k0 + bk, Bs + w * 512);
        __syncthreads();
        uint4 af = *(const uint4*)(As + (w * 16 + l15) * 32 + q * 8);
#pragma unroll
        for (int c = 0; c < 4; ++c) {
            uint4 bf = *(const uint4*)(Bs + (c * 16 + l15) * 32 + q * 8);
            acc[c] = mfma_bf16(af, bf, acc[c]);
        }
        __syncthreads();
    }

#pragma unroll
    for (int c = 0; c < 4; ++c) {
        int col = c0 + c * 16 + l15;
#pragma unroll
        for (int r = 0; r < 4; ++r) {
            int row = r0 + w * 16 + q * 4 + r;
            WfoldT[(long)row * 256 + col] = f2b(acc[c][r]);
        }
    }
}

// ---------------------------------------------------------------------------
// BatchNorm over lam^T[(b*256+e)][d]: stats per d over 2048 (b,e) values.
// ---------------------------------------------------------------------------
__global__ __launch_bounds__(256) void bn_kernel(const float* __restrict__ lamT,
                                                 const float* __restrict__ gamma,
                                                 const float* __restrict__ beta,
                                                 u16* __restrict__ bnT) {
    const int d = blockIdx.x;
    const int t = threadIdx.x;
    float vals[8];
    float s = 0.f, ss = 0.f;
#pragma unroll
    for (int i = 0; i < 8; ++i) {
        float v = lamT[(long)(i * 256 + t) * 256 + d];
        vals[i] = v;
        s += v;
        ss += v * v;
    }
#pragma unroll
    for (int sh = 32; sh > 0; sh >>= 1) {
        s += __shfl_xor(s, sh, 64);
        ss += __shfl_xor(ss, sh, 64);
    }
    __shared__ float red[8];
    int w = t >> 6;
    if ((t & 63) == 0) {
        red[w] = s;
        red[w + 4] = ss;
    }
    __syncthreads();
    s = red[0] + red[1] + red[2] + red[3];
    ss = red[4] + red[5] + red[6] + red[7];
    float mean = s * (1.f / 2048.f);
    float var = ss * (1.f / 2048.f) - mean * mean;
    float scale = gamma[d] * rsqrtf(var + 1e-5f);
    float shift = beta[d] - mean * scale;
#pragma unroll
    for (int i = 0; i < 8; ++i)
        bnT[(long)(i * 256 + t) * 256 + d] = f2b(vals[i] * scale + shift);
}

// ---------------------------------------------------------------------------
// outb[b][e] = sum_d bq[d] * bnT[b][e][d]   (folded query bias)
// ---------------------------------------------------------------------------
__global__ __launch_bounds__(256) void outb_kernel(const float* __restrict__ bq,
                                                   const u16* __restrict__ bnT,
                                                   float* __restrict__ outb) {
    int b = blockIdx.x, e = threadIdx.x;
    const u16* rowp = bnT + ((long)b * 256 + e) * 256;
    float s = 0.f;
    for (int dd = 0; dd < 256; ++dd) s += bq[dd] * b2f(rowp[dd]);
    outb[b * 256 + e] = s;
}

// ---------------------------------------------------------------------------
extern "C" void kernel_launch(void* const* d_in, const int* in_sizes, int n_in,
                              void* d_out, int out_size, void* d_ws, size_t ws_size,
                              hipStream_t stream) {
    const float* feat = (const float*)d_in[0];   // (8,8192,256) f32
    const float* W_qk = (const float*)d_in[1];   // (2,256,256) f32
    const float* b_qk = (const float*)d_in[2];   // (2,256) f32
    const float* W_v = (const float*)d_in[3];    // (256,256) f32
    const float* b_v = (const float*)d_in[4];    // (256,) f32
    const float* gamma = (const float*)d_in[5];  // (256,) f32
    const float* beta = (const float*)d_in[6];   // (256,) f32
    float* out = (float*)d_out;                  // (8,8192,256) f32

    char* ws = (char*)d_ws;
    u16* KT = (u16*)(ws);                        // tiled raw K, 33,554,432 B
    u16* VT = (u16*)(ws + 33554432);             // tiled V,     33,554,432 B
    u16* WkT = (u16*)(ws + 67108864);            // 131072 B
    u16* WvT = (u16*)(ws + 67239936);            // 131072 B
    u16* Wqb = (u16*)(ws + 67371008);            // 131072 B
    float* partial = (float*)(ws + 67502080);    // 2,097,152 B (m,s per chunk)
    float* ctab = (float*)(ws + 69599232);       // 8,192 B
    const size_t base = 69607424;
    float* lamP = (float*)(ws + base);           // S * 2,097,152 B
    size_t avail = (ws_size > base) ? ws_size - base : 0;
    int S = (avail >= 16u * 2097152u) ? 16
          : (avail >= 8u * 2097152u) ? 8
          : (avail >= 4u * 2097152u) ? 4 : 2;
    // post-split-K buffers alias the dead K region:
    float* lamT = (float*)ws;                    // 2,097,152 B
    u16* bnT = (u16*)(ws + 2097152);             // 1,048,576 B
    u16* WfoldT = (u16*)(ws + 3145728);          // 1,048,576 B
    float* outb = (float*)(ws + 4194304);        // 8,192 B

    // 1. weight prep
    prep_w<<<768, 256, 0, stream>>>(W_qk, W_v, WkT, WvT, Wqb);
    // 2. fused K/V projection -> tiled layout + softmax partials
    gemm_kv<<<1024, 256, 0, stream>>>(feat, WkT, WvT, b_qk + 256, b_v, KT, VT,
                                      partial);
    // 3. combine partials -> c[b][d]
    stats2<<<8, 256, 0, stream>>>(partial, ctab);
    // 4. split-K lam partials (P computed on the fly) + reduce
    gemm_splitk<<<dim3(16, 2, S), 256, 0, stream>>>(VT, KT, ctab, lamP, 8192 / S);
    reduce_lam<<<512, 256, 0, stream>>>(lamP, lamT, S);
    // 5. BN -> bn^T bf16
    bn_kernel<<<256, 256, 0, stream>>>(lamT, gamma, beta, bnT);
    // 6. folded query bias
    outb_kernel<<<8, 256, 0, stream>>>(b_qk, bnT, outb);
    // 7. Wfold^T = bn^T @ Wq^T
    gemm_fold<<<dim3(32, 4), 256, 0, stream>>>(bnT, Wqb, WfoldT);
    // 8. out = X @ Wfold (+outb)
    gemm_out<<<1024, 256, 0, stream>>>(feat, WfoldT, outb, out);
}

// Round 4
// 261.072 us; speedup vs baseline: 1.0921x; 1.0450x over previous
//
#include <hip/hip_runtime.h>

typedef unsigned short u16;
typedef __bf16 bf16x8 __attribute__((ext_vector_type(8)));
typedef float f32x4 __attribute__((ext_vector_type(4)));

#define LOG2E 1.44269504088896f

__device__ inline u16 f2b(float f) {
    unsigned u = __float_as_uint(f);
    u += 0x7fff + ((u >> 16) & 1);
    return (u16)(u >> 16);
}
__device__ inline float b2f(u16 u) { return __uint_as_float(((unsigned)u) << 16); }
__device__ inline unsigned pk2(float a, float b) {
    return (unsigned)f2b(a) | ((unsigned)f2b(b) << 16);
}
__device__ inline uint4 pack8(float4 a, float4 b) {
    return uint4{pk2(a.x, a.y), pk2(a.z, a.w), pk2(b.x, b.y), pk2(b.z, b.w)};
}
__device__ inline f32x4 mfma_bf16(uint4 a, uint4 b, f32x4 c) {
    return __builtin_amdgcn_mfma_f32_16x16x32_bf16(
        __builtin_bit_cast(bf16x8, a), __builtin_bit_cast(bf16x8, b), c, 0, 0, 0);
}
// async global->LDS, 16 B per lane; LDS dest = wave-uniform base + lane*16
__device__ inline void ld16(const u16* g, u16* l) {
    __builtin_amdgcn_global_load_lds(
        (const __attribute__((address_space(1))) unsigned int*)g,
        (__attribute__((address_space(3))) unsigned int*)l, 16, 0, 0);
}
// P = exp2(k*LOG2E - c) applied to a bf16x8 fragment (nc = -c), repacked bf16.
__device__ inline uint4 expfrag(uint4 v, float nc) {
    float e[8];
#pragma unroll
    for (int i = 0; i < 4; ++i) {
        unsigned u = ((const unsigned*)&v)[i];
        e[2 * i] = exp2f(fmaf(b2f((u16)(u & 0xffff)), LOG2E, nc));
        e[2 * i + 1] = exp2f(fmaf(b2f((u16)(u >> 16)), LOG2E, nc));
    }
    uint4 r;
    asm("v_cvt_pk_bf16_f32 %0, %1, %2" : "=v"(r.x) : "v"(e[0]), "v"(e[1]));
    asm("v_cvt_pk_bf16_f32 %0, %1, %2" : "=v"(r.y) : "v"(e[2]), "v"(e[3]));
    asm("v_cvt_pk_bf16_f32 %0, %1, %2" : "=v"(r.z) : "v"(e[4]), "v"(e[5]));
    asm("v_cvt_pk_bf16_f32 %0, %1, %2" : "=v"(r.w) : "v"(e[6]), "v"(e[7]));
    return r;
}

// Tiled intermediate layout: KT/VT [b][nt(256)][d(256)][n-in-tile(32)] bf16.
// Tile = 16 KB contiguous (d-major inside) -> streaming HBM writes from
// gemm_kv (2 tiles/block) and streaming 16-KB tile reads in gemm_lam.

// ---------------------------------------------------------------------------
// Weight prep (f32 -> bf16), plain layouts:
//   WkT[e][d] = Wqk[1][d][e],  WvT[e][d] = Wv[d][e],  Wqb[c][d] = Wqk[0][c][d]
// ---------------------------------------------------------------------------
__global__ __launch_bounds__(256) void prep_w(const float* __restrict__ Wqk,
                                              const float* __restrict__ Wv,
                                              u16* __restrict__ WkT,
                                              u16* __restrict__ WvT,
                                              u16* __restrict__ Wqb) {
    int idx = blockIdx.x * 256 + threadIdx.x;   // 0 .. 196607
    int which = idx >> 16;
    int i = (idx >> 8) & 255;
    int j = idx & 255;
    if (which == 0)
        WkT[i * 256 + j] = f2b(Wqk[65536 + j * 256 + i]);
    else if (which == 1)
        WvT[i * 256 + j] = f2b(Wv[j * 256 + i]);
    else
        Wqb[i * 256 + j] = f2b(Wqk[i * 256 + j]);
}

// ---------------------------------------------------------------------------
// Fused K+V projection (dbuf + swizzle + 4x4/wave tiling), TILED epilogue
// stores + fused per-block online-softmax partials for K.  (r3 verbatim)
// ---------------------------------------------------------------------------
__global__ __launch_bounds__(256, 2) void gemm_kv(const float* __restrict__ A,
                                                  const u16* __restrict__ BtK,
                                                  const u16* __restrict__ BtV,
                                                  const float* __restrict__ biasK,
                                                  const float* __restrict__ biasV,
                                                  u16* __restrict__ KT,
                                                  u16* __restrict__ VT,
                                                  float* __restrict__ partial) {
    __shared__ __align__(16) u16 lds[36864];

    const int t = threadIdx.x;
    const int r0 = blockIdx.x * 64;
    const int w = t >> 6, lane = t & 63, l15 = lane & 15, q = lane >> 4;
    const int sq = ((lane & 3) ^ ((lane >> 3) & 3)) * 8;  // staging src swizzle
    const int qs = (q ^ ((l15 >> 1) & 3)) * 8;            // frag read swizzle
    const int awoff = (t >> 2) * 32 + sq;                 // swizzled A ds_write
    const int brr = t >> 2;

    f32x4 accK[4][4], accV[4][4];
#pragma unroll
    for (int rt = 0; rt < 4; ++rt)
#pragma unroll
        for (int ct = 0; ct < 4; ++ct) {
            accK[rt][ct] = f32x4{0.f, 0.f, 0.f, 0.f};
            accV[rt][ct] = f32x4{0.f, 0.f, 0.f, 0.f};
        }

    const float* Arow = A + (long)(r0 + brr) * 256 + (t & 3) * 8;
    float4 p0 = ((const float4*)Arow)[0], p1 = ((const float4*)Arow)[1];
    float4 c0_ = *(const float4*)(Arow + 32), c1_ = *(const float4*)(Arow + 36);
    float4 d0_ = *(const float4*)(Arow + 64), d1_ = *(const float4*)(Arow + 68);

    // prologue: stage k0=0 into buffer 0
    {
        u16* dK = lds + 4096 + w * 512;
#pragma unroll
        for (int j = 0; j < 4; ++j) {
            int br = j * 64 + brr;
            ld16(BtK + br * 256 + sq, dK + j * 2048);
            ld16(BtV + br * 256 + sq, dK + 8192 + j * 2048);
        }
    }
    *(uint4*)(lds + awoff) = pack8(p0, p1);
    __syncthreads();

#pragma unroll
    for (int t8 = 0; t8 < 8; ++t8) {
        const int cur = t8 & 1;
        if (t8 < 7) {  // stage next k-slab into the other buffer (async)
            const int k0 = (t8 + 1) * 32;
            u16* dK = lds + 4096 + (cur ^ 1) * 16384 + w * 512;
#pragma unroll
            for (int j = 0; j < 4; ++j) {
                int br = j * 64 + brr;
                ld16(BtK + br * 256 + k0 + sq, dK + j * 2048);
                ld16(BtV + br * 256 + k0 + sq, dK + 8192 + j * 2048);
            }
            *(uint4*)(lds + (cur ^ 1) * 2048 + awoff) = pack8(c0_, c1_);
            c0_ = d0_; c1_ = d1_;
            if (t8 < 5) {
                d0_ = *(const float4*)(Arow + (t8 + 3) * 32);
                d1_ = *(const float4*)(Arow + (t8 + 3) * 32 + 4);
            }
        }
        const u16* Asc = lds + cur * 2048;
        const u16* Bc = lds + 4096 + cur * 16384;
        uint4 af[4];
#pragma unroll
        for (int rt = 0; rt < 4; ++rt)
            af[rt] = *(const uint4*)(Asc + (rt * 16 + l15) * 32 + qs);
#pragma unroll
        for (int ct = 0; ct < 4; ++ct) {
            const int bo = (w * 64 + ct * 16 + l15) * 32 + qs;
            uint4 bK = *(const uint4*)(Bc + bo);
            uint4 bV = *(const uint4*)(Bc + 8192 + bo);
#pragma unroll
            for (int rt = 0; rt < 4; ++rt) {
                accK[rt][ct] = mfma_bf16(af[rt], bK, accK[rt][ct]);
                accV[rt][ct] = mfma_bf16(af[rt], bV, accV[rt][ct]);
            }
        }
        __syncthreads();
    }

    // epilogue: bias + LDS transpose + TILED stores; pass 0 also emits
    // per-(b,d) online-softmax partials (m,s) over this block's 64 n.
    const int bb = r0 >> 13;
    const int nt0 = (r0 & 8191) >> 5;      // first of 2 tiles
    const int nch = nt0 >> 1;              // 0..127 partial slot
    u16* Ct = lds;
#pragma unroll
    for (int pass = 0; pass < 2; ++pass) {
        const f32x4(*acc)[4] = pass ? accV : accK;
        const float* bias = pass ? biasV : biasK;
        u16* CT = pass ? VT : KT;
#pragma unroll
        for (int ct = 0; ct < 4; ++ct) {
            const int col = w * 64 + ct * 16 + l15;
            const float bv = bias[col];
            ushort4 pks[4];
#pragma unroll
            for (int rt = 0; rt < 4; ++rt) {
                ushort4 pk;
                pk.x = f2b(acc[rt][ct][0] + bv);
                pk.y = f2b(acc[rt][ct][1] + bv);
                pk.z = f2b(acc[rt][ct][2] + bv);
                pk.w = f2b(acc[rt][ct][3] + bv);
                pks[rt] = pk;
                *(ushort4*)&Ct[col * 72 + rt * 16 + q * 4] = pk;
            }
            if (pass == 0) {
                float zm = -1e30f;
#pragma unroll
                for (int rt = 0; rt < 4; ++rt)
                    zm = fmaxf(zm,
                               fmaxf(fmaxf(b2f(pks[rt].x), b2f(pks[rt].y)),
                                     fmaxf(b2f(pks[rt].z), b2f(pks[rt].w))));
                zm = fmaxf(zm, __shfl_xor(zm, 16, 64));
                zm = fmaxf(zm, __shfl_xor(zm, 32, 64));
                zm *= LOG2E;   // z-space max
                float zs = 0.f;
#pragma unroll
                for (int rt = 0; rt < 4; ++rt) {
                    zs += exp2f(fmaf(b2f(pks[rt].x), LOG2E, -zm));
                    zs += exp2f(fmaf(b2f(pks[rt].y), LOG2E, -zm));
                    zs += exp2f(fmaf(b2f(pks[rt].z), LOG2E, -zm));
                    zs += exp2f(fmaf(b2f(pks[rt].w), LOG2E, -zm));
                }
                zs += __shfl_xor(zs, 16, 64);
                zs += __shfl_xor(zs, 32, 64);
                if (q == 0) {
                    float* pp =
                        partial + (((long)(bb * 128 + nch)) * 256 + col) * 2;
                    pp[0] = zm;
                    pp[1] = zs;
                }
            }
        }
        __syncthreads();
        {   // tiled store: CT[((bb*256 + nt0+j2)*256 + d)*32 + ...]
            const long tb = (((long)(bb * 256 + nt0)) * 256 + t) * 32;
#pragma unroll
            for (int j2 = 0; j2 < 2; ++j2)
#pragma unroll
                for (int g = 0; g < 4; ++g)
                    *(uint4*)(CT + tb + j2 * 8192 + g * 8) =
                        *(const uint4*)&Ct[t * 72 + j2 * 32 + g * 8];
        }
        __syncthreads();
    }
}

// ---------------------------------------------------------------------------
// Combine per-chunk softmax partials, PARALLEL: grid (8 b, 8 dgrp), 256 thr.
// Thread (ci = t>>5, d = dg*32 + (t&31)) online-merges 16 chunks; LDS-merge
// the 8 ci partials; c[b][d] = m + log2(s).
// ---------------------------------------------------------------------------
__global__ __launch_bounds__(256) void stats2(const float* __restrict__ partial,
                                              float* __restrict__ ctab) {
    const int b = blockIdx.x, dg = blockIdx.y;
    const int t = threadIdx.x;
    const int d = dg * 32 + (t & 31);
    const int ci = t >> 5;
    float m = -1e30f, sum = 0.f;
#pragma unroll 4
    for (int k = 0; k < 16; ++k) {
        int i = ci * 16 + k;
        const float* pp = partial + (((long)(b * 128 + i)) * 256 + d) * 2;
        float mi = pp[0], si = pp[1];
        float M = fmaxf(m, mi);
        sum = sum * exp2f(m - M) + si * exp2f(mi - M);
        m = M;
    }
    __shared__ float red[512];
    red[t] = m;
    red[t + 256] = sum;
    __syncthreads();
    if (ci == 0) {
#pragma unroll
        for (int j = 1; j < 8; ++j) {
            float mi = red[t + j * 32], si = red[t + 256 + j * 32];
            float M = fmaxf(m, mi);
            sum = sum * exp2f(m - M) + si * exp2f(mi - M);
            m = M;
        }
        ctab[b * 256 + d] = m + log2f(sum);
    }
}

// ---------------------------------------------------------------------------
// Output GEMM: out[b][n][e] = sum_c X[n][c]*WfoldT[(b,e)][c]+outb. (r1 verbatim)
// ---------------------------------------------------------------------------
__global__ __launch_bounds__(256, 3) void gemm_out(const float* __restrict__ A,
                                                   const u16* __restrict__ WfoldT,
                                                   const float* __restrict__ outb,
                                                   float* __restrict__ C) {
    __shared__ __align__(16) u16 lds[20480];
    const int t = threadIdx.x;
    const int r0 = blockIdx.x * 64;
    const int bb = r0 >> 13;
    const int w = t >> 6, lane = t & 63, l15 = lane & 15, q = lane >> 4;
    const int sq = ((lane & 3) ^ ((lane >> 3) & 3)) * 8;
    const int qs = (q ^ ((l15 >> 1) & 3)) * 8;
    const int awoff = (t >> 2) * 32 + sq;
    const int brr = t >> 2;
    const u16* Bt = WfoldT + (long)bb * 65536;

    f32x4 acc[4][4];
#pragma unroll
    for (int rt = 0; rt < 4; ++rt)
#pragma unroll
        for (int ct = 0; ct < 4; ++ct) acc[rt][ct] = f32x4{0.f, 0.f, 0.f, 0.f};

    const float* Arow = A + (long)(r0 + brr) * 256 + (t & 3) * 8;
    float4 p0 = ((const float4*)Arow)[0], p1 = ((const float4*)Arow)[1];
    float4 c0_ = *(const float4*)(Arow + 32), c1_ = *(const float4*)(Arow + 36);
    float4 d0_ = *(const float4*)(Arow + 64), d1_ = *(const float4*)(Arow + 68);

    {
        u16* dB = lds + 4096 + w * 512;
#pragma unroll
        for (int j = 0; j < 4; ++j)
            ld16(Bt + (j * 64 + brr) * 256 + sq, dB + j * 2048);
    }
    *(uint4*)(lds + awoff) = pack8(p0, p1);
    __syncthreads();

#pragma unroll
    for (int t8 = 0; t8 < 8; ++t8) {
        const int cur = t8 & 1;
        if (t8 < 7) {
            const int k0 = (t8 + 1) * 32;
            u16* dB = lds + 4096 + (cur ^ 1) * 8192 + w * 512;
#pragma unroll
            for (int j = 0; j < 4; ++j)
                ld16(Bt + (j * 64 + brr) * 256 + k0 + sq, dB + j * 2048);
            *(uint4*)(lds + (cur ^ 1) * 2048 + awoff) = pack8(c0_, c1_);
            c0_ = d0_; c1_ = d1_;
            if (t8 < 5) {
                d0_ = *(const float4*)(Arow + (t8 + 3) * 32);
                d1_ = *(const float4*)(Arow + (t8 + 3) * 32 + 4);
            }
        }
        const u16* Asc = lds + cur * 2048;
        const u16* Bc = lds + 4096 + cur * 8192;
        uint4 af[4];
#pragma unroll
        for (int rt = 0; rt < 4; ++rt)
            af[rt] = *(const uint4*)(Asc + (rt * 16 + l15) * 32 + qs);
#pragma unroll
        for (int ct = 0; ct < 4; ++ct) {
            uint4 bf = *(const uint4*)(Bc + (w * 64 + ct * 16 + l15) * 32 + qs);
#pragma unroll
            for (int rt = 0; rt < 4; ++rt)
                acc[rt][ct] = mfma_bf16(af[rt], bf, acc[rt][ct]);
        }
        __syncthreads();
    }

#pragma unroll
    for (int ct = 0; ct < 4; ++ct) {
        const int col = w * 64 + ct * 16 + l15;
        const float bv = outb[bb * 256 + col];
#pragma unroll
        for (int rt = 0; rt < 4; ++rt) {
            const long rbase = r0 + rt * 16 + q * 4;
#pragma unroll
            for (int r = 0; r < 4; ++r)
                C[(rbase + r) * 256 + col] = acc[rt][ct][r] + bv;
        }
    }
}

// ---------------------------------------------------------------------------
// lam GEMM, single-read: one block = FULL 256x256 lam tile for one (b, chunk).
// grid (8 b, S chunks) x 512 thr (8 waves as 2 e-groups x 4 d-groups; wave
// tile 128 e x 64 d, acc 8x4 frags).  Per 32-n k-step: stage one 16-KB V tile
// + one 16-KB K tile (contiguous, swizzled src), expfrag K->P on the fly.
// VT and KT are each read EXACTLY ONCE across the whole grid.
// ---------------------------------------------------------------------------
__global__ __launch_bounds__(512, 2) void gemm_lam(const u16* __restrict__ VT,
                                                   const u16* __restrict__ KT,
                                                   const float* __restrict__ ctab,
                                                   float* __restrict__ lamP,
                                                   int nk) {
    __shared__ __align__(16) u16 lds[32768];   // 2 buf x (V 8192 | K 8192) u16
    const int t = threadIdx.x;
    const int b = blockIdx.x;
    const int s = blockIdx.y;
    const int w = t >> 6, lane = t & 63, l15 = lane & 15, q = lane >> 4;
    const int eg = w >> 2, dg = w & 3;
    const int sq = ((lane & 3) ^ ((lane >> 3) & 3)) * 8;
    const int qs = (q ^ ((l15 >> 1) & 3)) * 8;

    const int nt0 = s * nk;
    const u16* Vb = VT + ((long)(b * 256 + nt0)) * 8192;   // 8192 u16 per tile
    const u16* Kb = KT + ((long)(b * 256 + nt0)) * 8192;

    float nc[4];
#pragma unroll
    for (int ct = 0; ct < 4; ++ct)
        nc[ct] = -ctab[b * 256 + dg * 64 + ct * 16 + l15];

    f32x4 acc[8][4];
#pragma unroll
    for (int rt = 0; rt < 8; ++rt)
#pragma unroll
        for (int ct = 0; ct < 4; ++ct) acc[rt][ct] = f32x4{0.f, 0.f, 0.f, 0.f};

    // stage one 16-KB tile: 1024 granules; granule g=(j*512+t): row=g>>2,
    // linear dest g*8; src pre-swizzled by sq (read side applies qs).
#define STAGE_TILE(tile, buf)                                                  \
    {                                                                          \
        _Pragma("unroll") for (int j = 0; j < 2; ++j) {                        \
            int g = j * 512 + t;                                               \
            ld16((tile) + (g >> 2) * 32 + sq, (buf) + (j * 512 + w * 64) * 8); \
        }                                                                      \
    }

    STAGE_TILE(Vb, lds)
    STAGE_TILE(Kb, lds + 8192)
    __syncthreads();

    for (int ks = 0; ks < nk; ++ks) {
        const int cur = ks & 1;
        if (ks + 1 < nk) {
            const u16* Vn = Vb + (long)(ks + 1) * 8192;
            const u16* Kn = Kb + (long)(ks + 1) * 8192;
            u16* dst = lds + (cur ^ 1) * 16384;
            STAGE_TILE(Vn, dst)
            STAGE_TILE(Kn, dst + 8192)
        }
        const u16* Vs = lds + cur * 16384;
        const u16* Ks = Vs + 8192;
        uint4 bf[4];
#pragma unroll
        for (int ct = 0; ct < 4; ++ct)
            bf[ct] = expfrag(
                *(const uint4*)(Ks + (dg * 64 + ct * 16 + l15) * 32 + qs),
                nc[ct]);
#pragma unroll
        for (int rt = 0; rt < 8; ++rt) {
            uint4 af = *(const uint4*)(Vs + (eg * 128 + rt * 16 + l15) * 32 + qs);
#pragma unroll
            for (int ct = 0; ct < 4; ++ct)
                acc[rt][ct] = mfma_bf16(af, bf[ct], acc[rt][ct]);
        }
        __syncthreads();
    }
#undef STAGE_TILE

    // store partial lam[s]: rows (b,e), cols d
    float* outp = lamP + (long)s * 524288 + (long)b * 65536;
#pragma unroll
    for (int rt = 0; rt < 8; ++rt)
#pragma unroll
        for (int ct = 0; ct < 4; ++ct) {
            const int col = dg * 64 + ct * 16 + l15;
            const int row = eg * 128 + rt * 16 + q * 4;
#pragma unroll
            for (int r = 0; r < 4; ++r)
                outp[(long)(row + r) * 256 + col] = acc[rt][ct][r];
        }
}

// ---------------------------------------------------------------------------
// lamT[i] = sum_s lamP[s][i]   (coalesced float4)
// ---------------------------------------------------------------------------
__global__ __launch_bounds__(256) void reduce_lam(const float* __restrict__ lamP,
                                                  float* __restrict__ lamT, int S) {
    int i = blockIdx.x * 256 + threadIdx.x;  // float4 index, 131072 total
    float4 v = ((const float4*)lamP)[i];
    for (int s = 1; s < S; ++s) {
        float4 p = ((const float4*)(lamP + (long)s * 524288))[i];
        v.x += p.x; v.y += p.y; v.z += p.z; v.w += p.w;
    }
    ((float4*)lamT)[i] = v;
}

// ---------------------------------------------------------------------------
// Fold GEMM: WfoldT[(b,e)][c] = sum_d bnT[(b,e)][d] * Wqb[c][d]. (r1 verbatim)
// ---------------------------------------------------------------------------
__global__ __launch_bounds__(256, 4) void gemm_fold(const u16* __restrict__ Abn,
                                                    const u16* __restrict__ Wqb,
                                                    u16* __restrict__ WfoldT) {
    __shared__ __align__(16) u16 lds[4096];  // As 64x32, Bs 64x32
    u16* As = lds;
    u16* Bs = lds + 2048;

    const int t = threadIdx.x;
    const int r0 = blockIdx.x * 64;
    const int c0 = blockIdx.y * 64;
    const int w = t >> 6, lane = t & 63, l15 = lane & 15, q = lane >> 4;

    f32x4 acc[4];
#pragma unroll
    for (int c = 0; c < 4; ++c) acc[c] = f32x4{0.f, 0.f, 0.f, 0.f};

    const int br = t >> 2;
    const int bk = (t & 3) * 8;

    for (int k0 = 0; k0 < 256; k0 += 32) {
        ld16(Abn + (long)(r0 + br) * 256 + k0 + bk, As + w * 512);
        ld16(Wqb + (long)(c0 + br) * 256 + k0 + bk, Bs + w * 512);
        __syncthreads();
        uint4 af = *(const uint4*)(As + (w * 16 + l15) * 32 + q * 8);
#pragma unroll
        for (int c = 0; c < 4; ++c) {
            uint4 bf = *(const uint4*)(Bs + (c * 16 + l15) * 32 + q * 8);
            acc[c] = mfma_bf16(af, bf, acc[c]);
        }
        __syncthreads();
    }

#pragma unroll
    for (int c = 0; c < 4; ++c) {
        int col = c0 + c * 16 + l15;
#pragma unroll
        for (int r = 0; r < 4; ++r) {
            int row = r0 + w * 16 + q * 4 + r;
            WfoldT[(long)row * 256 + col] = f2b(acc[c][r]);
        }
    }
}

// ---------------------------------------------------------------------------
// BatchNorm over lam^T[(b*256+e)][d]: stats per d over 2048 (b,e) values.
// ---------------------------------------------------------------------------
__global__ __launch_bounds__(256) void bn_kernel(const float* __restrict__ lamT,
                                                 const float* __restrict__ gamma,
                                                 const float* __restrict__ beta,
                                                 u16* __restrict__ bnT) {
    const int d = blockIdx.x;
    const int t = threadIdx.x;
    float vals[8];
    float s = 0.f, ss = 0.f;
#pragma unroll
    for (int i = 0; i < 8; ++i) {
        float v = lamT[(long)(i * 256 + t) * 256 + d];
        vals[i] = v;
        s += v;
        ss += v * v;
    }
#pragma unroll
    for (int sh = 32; sh > 0; sh >>= 1) {
        s += __shfl_xor(s, sh, 64);
        ss += __shfl_xor(ss, sh, 64);
    }
    __shared__ float red[8];
    int w = t >> 6;
    if ((t & 63) == 0) {
        red[w] = s;
        red[w + 4] = ss;
    }
    __syncthreads();
    s = red[0] + red[1] + red[2] + red[3];
    ss = red[4] + red[5] + red[6] + red[7];
    float mean = s * (1.f / 2048.f);
    float var = ss * (1.f / 2048.f) - mean * mean;
    float scale = gamma[d] * rsqrtf(var + 1e-5f);
    float shift = beta[d] - mean * scale;
#pragma unroll
    for (int i = 0; i < 8; ++i)
        bnT[(long)(i * 256 + t) * 256 + d] = f2b(vals[i] * scale + shift);
}

// ---------------------------------------------------------------------------
// outb[b][e] = sum_d bq[d] * bnT[b][e][d]   (folded query bias)
// ---------------------------------------------------------------------------
__global__ __launch_bounds__(256) void outb_kernel(const float* __restrict__ bq,
                                                   const u16* __restrict__ bnT,
                                                   float* __restrict__ outb) {
    int b = blockIdx.x, e = threadIdx.x;
    const u16* rowp = bnT + ((long)b * 256 + e) * 256;
    float s = 0.f;
    for (int dd = 0; dd < 256; ++dd) s += bq[dd] * b2f(rowp[dd]);
    outb[b * 256 + e] = s;
}

// ---------------------------------------------------------------------------
extern "C" void kernel_launch(void* const* d_in, const int* in_sizes, int n_in,
                              void* d_out, int out_size, void* d_ws, size_t ws_size,
                              hipStream_t stream) {
    const float* feat = (const float*)d_in[0];   // (8,8192,256) f32
    const float* W_qk = (const float*)d_in[1];   // (2,256,256) f32
    const float* b_qk = (const float*)d_in[2];   // (2,256) f32
    const float* W_v = (const float*)d_in[3];    // (256,256) f32
    const float* b_v = (const float*)d_in[4];    // (256,) f32
    const float* gamma = (const float*)d_in[5];  // (256,) f32
    const float* beta = (const float*)d_in[6];   // (256,) f32
    float* out = (float*)d_out;                  // (8,8192,256) f32

    char* ws = (char*)d_ws;
    u16* KT = (u16*)(ws);                        // tiled raw K, 33,554,432 B
    u16* VT = (u16*)(ws + 33554432);             // tiled V,     33,554,432 B
    u16* WkT = (u16*)(ws + 67108864);            // 131072 B
    u16* WvT = (u16*)(ws + 67239936);            // 131072 B
    u16* Wqb = (u16*)(ws + 67371008);            // 131072 B
    float* partial = (float*)(ws + 67502080);    // 2,097,152 B (m,s per chunk)
    float* ctab = (float*)(ws + 69599232);       // 8,192 B
    const size_t base = 69607424;
    float* lamP = (float*)(ws + base);           // S * 2,097,152 B
    size_t avail = (ws_size > base) ? ws_size - base : 0;
    int S = (avail >= 16u * 2097152u) ? 16
          : (avail >= 8u * 2097152u) ? 8
          : (avail >= 4u * 2097152u) ? 4 : 2;
    // post-lam buffers alias the dead K region (only written after gemm_lam):
    float* lamT = (float*)ws;                    // 2,097,152 B
    u16* bnT = (u16*)(ws + 2097152);             // 1,048,576 B
    u16* WfoldT = (u16*)(ws + 3145728);          // 1,048,576 B
    float* outb = (float*)(ws + 4194304);        // 8,192 B

    // 1. weight prep
    prep_w<<<768, 256, 0, stream>>>(W_qk, W_v, WkT, WvT, Wqb);
    // 2. fused K/V projection -> tiled layout + softmax partials
    gemm_kv<<<1024, 256, 0, stream>>>(feat, WkT, WvT, b_qk + 256, b_v, KT, VT,
                                      partial);
    // 3. combine partials -> c[b][d]  (parallel)
    stats2<<<dim3(8, 8), 256, 0, stream>>>(partial, ctab);
    // 4. lam partials, single-read (P computed on the fly) + reduce
    gemm_lam<<<dim3(8, S), 512, 0, stream>>>(VT, KT, ctab, lamP, 8192 / S / 32);
    reduce_lam<<<512, 256, 0, stream>>>(lamP, lamT, S);
    // 5. BN -> bn^T bf16
    bn_kernel<<<256, 256, 0, stream>>>(lamT, gamma, beta, bnT);
    // 6. folded query bias
    outb_kernel<<<8, 256, 0, stream>>>(b_qk, bnT, outb);
    // 7. Wfold^T = bn^T @ Wq^T
    gemm_fold<<<dim3(32, 4), 256, 0, stream>>>(bnT, Wqb, WfoldT);
    // 8. out = X @ Wfold (+outb)
    gemm_out<<<1024, 256, 0, stream>>>(feat, WfoldT, outb, out);
}

// Round 5
// 257.381 us; speedup vs baseline: 1.1077x; 1.0143x over previous
//
#include <hip/hip_runtime.h>

typedef unsigned short u16;
typedef __bf16 bf16x8 __attribute__((ext_vector_type(8)));
typedef float f32x4 __attribute__((ext_vector_type(4)));

#define LOG2E 1.44269504088896f

__device__ inline u16 f2b(float f) {
    unsigned u = __float_as_uint(f);
    u += 0x7fff + ((u >> 16) & 1);
    return (u16)(u >> 16);
}
__device__ inline float b2f(u16 u) { return __uint_as_float(((unsigned)u) << 16); }
__device__ inline f32x4 mfma_bf16(uint4 a, uint4 b, f32x4 c) {
    return __builtin_amdgcn_mfma_f32_16x16x32_bf16(
        __builtin_bit_cast(bf16x8, a), __builtin_bit_cast(bf16x8, b), c, 0, 0, 0);
}
// async global->LDS, 16 B per lane; LDS dest = wave-uniform base + lane*16
__device__ inline void ld16(const u16* g, u16* l) {
    __builtin_amdgcn_global_load_lds(
        (const __attribute__((address_space(1))) unsigned int*)g,
        (__attribute__((address_space(3))) unsigned int*)l, 16, 0, 0);
}
// P = exp2(k*LOG2E - c) applied to a bf16x8 fragment (nc = -c), repacked bf16.
__device__ inline uint4 expfrag(uint4 v, float nc) {
    float e[8];
#pragma unroll
    for (int i = 0; i < 4; ++i) {
        unsigned u = ((const unsigned*)&v)[i];
        e[2 * i] = exp2f(fmaf(b2f((u16)(u & 0xffff)), LOG2E, nc));
        e[2 * i + 1] = exp2f(fmaf(b2f((u16)(u >> 16)), LOG2E, nc));
    }
    uint4 r;
    asm("v_cvt_pk_bf16_f32 %0, %1, %2" : "=v"(r.x) : "v"(e[0]), "v"(e[1]));
    asm("v_cvt_pk_bf16_f32 %0, %1, %2" : "=v"(r.y) : "v"(e[2]), "v"(e[3]));
    asm("v_cvt_pk_bf16_f32 %0, %1, %2" : "=v"(r.z) : "v"(e[4]), "v"(e[5]));
    asm("v_cvt_pk_bf16_f32 %0, %1, %2" : "=v"(r.w) : "v"(e[6]), "v"(e[7]));
    return r;
}

// Tiled intermediate layout: KT/VT [b][nt(256)][d(256)][n-in-tile(32)] bf16.

// ---------------------------------------------------------------------------
// Weight prep (f32 -> bf16), plain layouts:
//   WkT[e][d] = Wqk[1][d][e],  WvT[e][d] = Wv[d][e],  Wqb[c][d] = Wqk[0][c][d]
// ---------------------------------------------------------------------------
__global__ __launch_bounds__(256) void prep_w(const float* __restrict__ Wqk,
                                              const float* __restrict__ Wv,
                                              u16* __restrict__ WkT,
                                              u16* __restrict__ WvT,
                                              u16* __restrict__ Wqb) {
    int idx = blockIdx.x * 256 + threadIdx.x;   // 0 .. 196607
    int which = idx >> 16;
    int i = (idx >> 8) & 255;
    int j = idx & 255;
    if (which == 0)
        WkT[i * 256 + j] = f2b(Wqk[65536 + j * 256 + i]);
    else if (which == 1)
        WvT[i * 256 + j] = f2b(Wv[j * 256 + i]);
    else
        Wqb[i * 256 + j] = f2b(Wqk[i * 256 + j]);
}

// ---------------------------------------------------------------------------
// Fused K+V projection v5: 512 thr / 8 waves; wave w owns mat (w&1) x 64 cols
// (cg=w>>1) -> acc 16 frags = 64 regs/wave -> 4 waves/SIMD at __launch_bounds__
// (512,4).  LDS 36 KB (As[64][32] single + BsK/BsV single), r0's proven
// 2-barrier schedule.  Tiled epilogue stores + fused softmax partials (K).
// ---------------------------------------------------------------------------
__global__ __launch_bounds__(512, 4) void gemm_kv(const float* __restrict__ A,
                                                  const u16* __restrict__ BtK,
                                                  const u16* __restrict__ BtV,
                                                  const float* __restrict__ biasK,
                                                  const float* __restrict__ biasV,
                                                  u16* __restrict__ KT,
                                                  u16* __restrict__ VT,
                                                  float* __restrict__ partial) {
    __shared__ __align__(16) u16 lds[18432];  // As@0 (2048) | BsK@2048 | BsV@10240

    const int t = threadIdx.x;
    const int r0 = blockIdx.x * 64;
    const int w = t >> 6, lane = t & 63, l15 = lane & 15, q = lane >> 4;
    const int mat = w & 1, cg = w >> 1;
    const int sq = ((lane & 3) ^ ((lane >> 3) & 3)) * 8;  // staging src swizzle
    const int qs = (q ^ ((l15 >> 1) & 3)) * 8;            // frag read swizzle
    // A staging: thread t -> row t>>3, k-slice (t&7)*4 (4 f32 -> 8 B bf16)
    const int arow = t >> 3;
    const int aq = ((t & 7) >> 1) ^ ((arow >> 1) & 3);    // swizzled 16B slot
    const int awoff = arow * 32 + aq * 8 + (t & 1) * 4;
    const float* Ap = A + (long)(r0 + arow) * 256 + (t & 7) * 4;
    const u16* Bs = lds + 2048 + mat * 8192;              // this wave's B tile

    f32x4 acc[4][4];
#pragma unroll
    for (int rt = 0; rt < 4; ++rt)
#pragma unroll
        for (int ct = 0; ct < 4; ++ct) acc[rt][ct] = f32x4{0.f, 0.f, 0.f, 0.f};

    float4 a = *(const float4*)Ap;
    for (int ks = 0; ks < 8; ++ks) {
        const int k0 = ks * 32;
        // stage both weight slabs (all threads cooperate)
#pragma unroll
        for (int j = 0; j < 2; ++j) {
            const int src = (j * 128 + (t >> 2)) * 256 + k0 + sq;
            ld16(BtK + src, lds + 2048 + j * 4096 + w * 512);
            ld16(BtV + src, lds + 10240 + j * 4096 + w * 512);
        }
        *(ushort4*)&lds[awoff] = ushort4{f2b(a.x), f2b(a.y), f2b(a.z), f2b(a.w)};
        __syncthreads();
        if (ks < 7) a = *(const float4*)(Ap + k0 + 32);
        uint4 af[4];
#pragma unroll
        for (int rt = 0; rt < 4; ++rt)
            af[rt] = *(const uint4*)(lds + (rt * 16 + l15) * 32 + qs);
#pragma unroll
        for (int ct = 0; ct < 4; ++ct) {
            uint4 bf = *(const uint4*)(Bs + (cg * 64 + ct * 16 + l15) * 32 + qs);
#pragma unroll
            for (int rt = 0; rt < 4; ++rt)
                acc[rt][ct] = mfma_bf16(af[rt], bf, acc[rt][ct]);
        }
        __syncthreads();
    }

    // epilogue: bias + LDS transpose (Ct 256x72 = 18432 u16) + tiled stores;
    // pass 0 (K) also emits per-(b,d) online-softmax partials over 64 n.
    const int bb = r0 >> 13;
    const int nt0 = (r0 & 8191) >> 5;
    const int nch = nt0 >> 1;
    const float* bias = mat ? biasV : biasK;
#pragma unroll
    for (int pass = 0; pass < 2; ++pass) {
        if (mat == pass) {
#pragma unroll
            for (int ct = 0; ct < 4; ++ct) {
                const int col = cg * 64 + ct * 16 + l15;
                const float bv = bias[col];
                ushort4 pks[4];
#pragma unroll
                for (int rt = 0; rt < 4; ++rt) {
                    ushort4 pk;
                    pk.x = f2b(acc[rt][ct][0] + bv);
                    pk.y = f2b(acc[rt][ct][1] + bv);
                    pk.z = f2b(acc[rt][ct][2] + bv);
                    pk.w = f2b(acc[rt][ct][3] + bv);
                    pks[rt] = pk;
                    *(ushort4*)&lds[col * 72 + rt * 16 + q * 4] = pk;
                }
                if (pass == 0) {
                    float zm = -1e30f;
#pragma unroll
                    for (int rt = 0; rt < 4; ++rt)
                        zm = fmaxf(zm,
                                   fmaxf(fmaxf(b2f(pks[rt].x), b2f(pks[rt].y)),
                                         fmaxf(b2f(pks[rt].z), b2f(pks[rt].w))));
                    zm = fmaxf(zm, __shfl_xor(zm, 16, 64));
                    zm = fmaxf(zm, __shfl_xor(zm, 32, 64));
                    zm *= LOG2E;   // z-space max
                    float zs = 0.f;
#pragma unroll
                    for (int rt = 0; rt < 4; ++rt) {
                        zs += exp2f(fmaf(b2f(pks[rt].x), LOG2E, -zm));
                        zs += exp2f(fmaf(b2f(pks[rt].y), LOG2E, -zm));
                        zs += exp2f(fmaf(b2f(pks[rt].z), LOG2E, -zm));
                        zs += exp2f(fmaf(b2f(pks[rt].w), LOG2E, -zm));
                    }
                    zs += __shfl_xor(zs, 16, 64);
                    zs += __shfl_xor(zs, 32, 64);
                    if (q == 0) {
                        float* pp =
                            partial + (((long)(bb * 128 + nch)) * 256 + col) * 2;
                        pp[0] = zm;
                        pp[1] = zs;
                    }
                }
            }
        }
        __syncthreads();
        {   // tiled readout: 512 thr, thread t -> (d = t>>1, tile j2 = t&1)
            u16* CT = pass ? VT : KT;
            const int d = t >> 1, j2 = t & 1;
            const long dst = (((long)(bb * 256 + nt0 + j2)) * 256 + d) * 32;
#pragma unroll
            for (int g = 0; g < 4; ++g)
                *(uint4*)(CT + dst + g * 8) =
                    *(const uint4*)&lds[d * 72 + j2 * 32 + g * 8];
        }
        __syncthreads();
    }
}

// ---------------------------------------------------------------------------
// Combine per-chunk softmax partials, PARALLEL: grid (8 b, 8 dgrp), 256 thr.
// ---------------------------------------------------------------------------
__global__ __launch_bounds__(256) void stats2(const float* __restrict__ partial,
                                              float* __restrict__ ctab) {
    const int b = blockIdx.x, dg = blockIdx.y;
    const int t = threadIdx.x;
    const int d = dg * 32 + (t & 31);
    const int ci = t >> 5;
    float m = -1e30f, sum = 0.f;
#pragma unroll 4
    for (int k = 0; k < 16; ++k) {
        int i = ci * 16 + k;
        const float* pp = partial + (((long)(b * 128 + i)) * 256 + d) * 2;
        float mi = pp[0], si = pp[1];
        float M = fmaxf(m, mi);
        sum = sum * exp2f(m - M) + si * exp2f(mi - M);
        m = M;
    }
    __shared__ float red[512];
    red[t] = m;
    red[t + 256] = sum;
    __syncthreads();
    if (ci == 0) {
#pragma unroll
        for (int j = 1; j < 8; ++j) {
            float mi = red[t + j * 32], si = red[t + 256 + j * 32];
            float M = fmaxf(m, mi);
            sum = sum * exp2f(m - M) + si * exp2f(mi - M);
            m = M;
        }
        ctab[b * 256 + d] = m + log2f(sum);
    }
}

// ---------------------------------------------------------------------------
// Output GEMM: out[b][n][e] = sum_c X[n][c]*WfoldT[(b,e)][c]+outb. (unchanged)
// ---------------------------------------------------------------------------
__global__ __launch_bounds__(256, 3) void gemm_out(const float* __restrict__ A,
                                                   const u16* __restrict__ WfoldT,
                                                   const float* __restrict__ outb,
                                                   float* __restrict__ C) {
    __shared__ __align__(16) u16 lds[20480];
    const int t = threadIdx.x;
    const int r0 = blockIdx.x * 64;
    const int bb = r0 >> 13;
    const int w = t >> 6, lane = t & 63, l15 = lane & 15, q = lane >> 4;
    const int sq = ((lane & 3) ^ ((lane >> 3) & 3)) * 8;
    const int qs = (q ^ ((l15 >> 1) & 3)) * 8;
    const int awoff = (t >> 2) * 32 + sq;
    const int brr = t >> 2;
    const u16* Bt = WfoldT + (long)bb * 65536;

    f32x4 acc[4][4];
#pragma unroll
    for (int rt = 0; rt < 4; ++rt)
#pragma unroll
        for (int ct = 0; ct < 4; ++ct) acc[rt][ct] = f32x4{0.f, 0.f, 0.f, 0.f};

    const float* Arow = A + (long)(r0 + brr) * 256 + (t & 3) * 8;
    float4 p0 = ((const float4*)Arow)[0], p1 = ((const float4*)Arow)[1];
    float4 c0_ = *(const float4*)(Arow + 32), c1_ = *(const float4*)(Arow + 36);
    float4 d0_ = *(const float4*)(Arow + 64), d1_ = *(const float4*)(Arow + 68);

    {
        u16* dB = lds + 4096 + w * 512;
#pragma unroll
        for (int j = 0; j < 4; ++j)
            ld16(Bt + (j * 64 + brr) * 256 + sq, dB + j * 2048);
    }
    {
        ushort4 lo{f2b(p0.x), f2b(p0.y), f2b(p0.z), f2b(p0.w)};
        ushort4 hi{f2b(p1.x), f2b(p1.y), f2b(p1.z), f2b(p1.w)};
        *(ushort4*)&lds[awoff] = lo;
        *(ushort4*)&lds[awoff + 4] = hi;
    }
    __syncthreads();

#pragma unroll
    for (int t8 = 0; t8 < 8; ++t8) {
        const int cur = t8 & 1;
        if (t8 < 7) {
            const int k0 = (t8 + 1) * 32;
            u16* dB = lds + 4096 + (cur ^ 1) * 8192 + w * 512;
#pragma unroll
            for (int j = 0; j < 4; ++j)
                ld16(Bt + (j * 64 + brr) * 256 + k0 + sq, dB + j * 2048);
            ushort4 lo{f2b(c0_.x), f2b(c0_.y), f2b(c0_.z), f2b(c0_.w)};
            ushort4 hi{f2b(c1_.x), f2b(c1_.y), f2b(c1_.z), f2b(c1_.w)};
            *(ushort4*)&lds[(cur ^ 1) * 2048 + awoff] = lo;
            *(ushort4*)&lds[(cur ^ 1) * 2048 + awoff + 4] = hi;
            c0_ = d0_; c1_ = d1_;
            if (t8 < 5) {
                d0_ = *(const float4*)(Arow + (t8 + 3) * 32);
                d1_ = *(const float4*)(Arow + (t8 + 3) * 32 + 4);
            }
        }
        const u16* Asc = lds + cur * 2048;
        const u16* Bc = lds + 4096 + cur * 8192;
        uint4 af[4];
#pragma unroll
        for (int rt = 0; rt < 4; ++rt)
            af[rt] = *(const uint4*)(Asc + (rt * 16 + l15) * 32 + qs);
#pragma unroll
        for (int ct = 0; ct < 4; ++ct) {
            uint4 bf = *(const uint4*)(Bc + (w * 64 + ct * 16 + l15) * 32 + qs);
#pragma unroll
            for (int rt = 0; rt < 4; ++rt)
                acc[rt][ct] = mfma_bf16(af[rt], bf, acc[rt][ct]);
        }
        __syncthreads();
    }

#pragma unroll
    for (int ct = 0; ct < 4; ++ct) {
        const int col = w * 64 + ct * 16 + l15;
        const float bv = outb[bb * 256 + col];
#pragma unroll
        for (int rt = 0; rt < 4; ++rt) {
            const long rbase = r0 + rt * 16 + q * 4;
#pragma unroll
            for (int r = 0; r < 4; ++r)
                C[(rbase + r) * 256 + col] = acc[rt][ct][r] + bv;
        }
    }
}

// ---------------------------------------------------------------------------
// lam GEMM v5: grid (64 = b x eh x dh, S) x 256 thr, block = 64 e x 128 d.
// acc 8 frags = 32 regs/wave, LDS 24 KB dbuf -> up to 24 waves/CU; full-GPU
// coverage (512 blocks at S=8).  VT read once; KT read twice (eh pairs, L3).
// P = exp2(k*LOG2E - c) on the fly via expfrag.
// ---------------------------------------------------------------------------
__global__ __launch_bounds__(256, 6) void gemm_lam(const u16* __restrict__ VT,
                                                   const u16* __restrict__ KT,
                                                   const float* __restrict__ ctab,
                                                   float* __restrict__ lamP,
                                                   int nk) {
    __shared__ __align__(16) u16 lds[12288];  // dbuf x (Vs 2048 | Ks 4096)
    const int t = threadIdx.x;
    const int bx = blockIdx.x;
    const int b = bx >> 3, e0 = ((bx >> 1) & 3) * 64, d0 = (bx & 1) * 128;
    const int s = blockIdx.y;
    const int w = t >> 6, lane = t & 63, l15 = lane & 15, q = lane >> 4;
    const int sq = ((lane & 3) ^ ((lane >> 3) & 3)) * 8;
    const int qs = (q ^ ((l15 >> 1) & 3)) * 8;

    const long nt0 = (long)s * nk;
    const u16* Vb = VT + ((long)b * 256 + nt0) * 8192;
    const u16* Kb = KT + ((long)b * 256 + nt0) * 8192;

    float nc0 = -ctab[b * 256 + d0 + w * 32 + l15];
    float nc1 = -ctab[b * 256 + d0 + w * 32 + 16 + l15];

    f32x4 acc[4][2];
#pragma unroll
    for (int rt = 0; rt < 4; ++rt) {
        acc[rt][0] = f32x4{0.f, 0.f, 0.f, 0.f};
        acc[rt][1] = f32x4{0.f, 0.f, 0.f, 0.f};
    }

    // prologue: stage tile 0 into buf 0
    ld16(Vb + (e0 + (t >> 2)) * 32 + sq, lds + w * 512);
    ld16(Kb + (d0 + (t >> 2)) * 32 + sq, lds + 2048 + w * 512);
    ld16(Kb + (d0 + 64 + (t >> 2)) * 32 + sq, lds + 4096 + w * 512);
    __syncthreads();

    for (int ks = 0; ks < nk; ++ks) {
        const int cur = ks & 1;
        if (ks + 1 < nk) {
            const u16* Vn = Vb + (long)(ks + 1) * 8192;
            const u16* Kn = Kb + (long)(ks + 1) * 8192;
            u16* dst = lds + (cur ^ 1) * 6144;
            ld16(Vn + (e0 + (t >> 2)) * 32 + sq, dst + w * 512);
            ld16(Kn + (d0 + (t >> 2)) * 32 + sq, dst + 2048 + w * 512);
            ld16(Kn + (d0 + 64 + (t >> 2)) * 32 + sq, dst + 4096 + w * 512);
        }
        const u16* Vs = lds + cur * 6144;
        const u16* Ks = Vs + 2048;
        uint4 bf0 = expfrag(*(const uint4*)(Ks + (w * 32 + l15) * 32 + qs), nc0);
        uint4 bf1 =
            expfrag(*(const uint4*)(Ks + (w * 32 + 16 + l15) * 32 + qs), nc1);
#pragma unroll
        for (int rt = 0; rt < 4; ++rt) {
            uint4 af = *(const uint4*)(Vs + (rt * 16 + l15) * 32 + qs);
            acc[rt][0] = mfma_bf16(af, bf0, acc[rt][0]);
            acc[rt][1] = mfma_bf16(af, bf1, acc[rt][1]);
        }
        __syncthreads();
    }

    // store partial lam[s]: rows (b, e0+..), cols d0+..
    float* outp = lamP + (long)s * 524288 + (long)b * 65536;
#pragma unroll
    for (int rt = 0; rt < 4; ++rt)
#pragma unroll
        for (int ct = 0; ct < 2; ++ct) {
            const int col = d0 + w * 32 + ct * 16 + l15;
            const int row = e0 + rt * 16 + q * 4;
#pragma unroll
            for (int r = 0; r < 4; ++r)
                outp[(long)(row + r) * 256 + col] = acc[rt][ct][r];
        }
}

// ---------------------------------------------------------------------------
// lamT[i] = sum_s lamP[s][i]   (coalesced float4)
// ---------------------------------------------------------------------------
__global__ __launch_bounds__(256) void reduce_lam(const float* __restrict__ lamP,
                                                  float* __restrict__ lamT, int S) {
    int i = blockIdx.x * 256 + threadIdx.x;  // float4 index, 131072 total
    float4 v = ((const float4*)lamP)[i];
    for (int s = 1; s < S; ++s) {
        float4 p = ((const float4*)(lamP + (long)s * 524288))[i];
        v.x += p.x; v.y += p.y; v.z += p.z; v.w += p.w;
    }
    ((float4*)lamT)[i] = v;
}

// ---------------------------------------------------------------------------
// Fold GEMM: WfoldT[(b,e)][c] = sum_d bnT[(b,e)][d] * Wqb[c][d]. (unchanged)
// ---------------------------------------------------------------------------
__global__ __launch_bounds__(256, 4) void gemm_fold(const u16* __restrict__ Abn,
                                                    const u16* __restrict__ Wqb,
                                                    u16* __restrict__ WfoldT) {
    __shared__ __align__(16) u16 lds[4096];  // As 64x32, Bs 64x32
    u16* As = lds;
    u16* Bs = lds + 2048;

    const int t = threadIdx.x;
    const int r0 = blockIdx.x * 64;
    const int c0 = blockIdx.y * 64;
    const int w = t >> 6, lane = t & 63, l15 = lane & 15, q = lane >> 4;

    f32x4 acc[4];
#pragma unroll
    for (int c = 0; c < 4; ++c) acc[c] = f32x4{0.f, 0.f, 0.f, 0.f};

    const int br = t >> 2;
    const int bk = (t & 3) * 8;

    for (int k0 = 0; k0 < 256; k0 += 32) {
        ld16(Abn + (long)(r0 + br) * 256 + k0 + bk, As + w * 512);
        ld16(Wqb + (long)(c0 + br) * 256 + k0 + bk, Bs + w * 512);
        __syncthreads();
        uint4 af = *(const uint4*)(As + (w * 16 + l15) * 32 + q * 8);
#pragma unroll
        for (int c = 0; c < 4; ++c) {
            uint4 bf = *(const uint4*)(Bs + (c * 16 + l15) * 32 + q * 8);
            acc[c] = mfma_bf16(af, bf, acc[c]);
        }
        __syncthreads();
    }

#pragma unroll
    for (int c = 0; c < 4; ++c) {
        int col = c0 + c * 16 + l15;
#pragma unroll
        for (int r = 0; r < 4; ++r) {
            int row = r0 + w * 16 + q * 4 + r;
            WfoldT[(long)row * 256 + col] = f2b(acc[c][r]);
        }
    }
}

// ---------------------------------------------------------------------------
// BatchNorm over lam^T[(b*256+e)][d]: stats per d over 2048 (b,e) values.
// ---------------------------------------------------------------------------
__global__ __launch_bounds__(256) void bn_kernel(const float* __restrict__ lamT,
                                                 const float* __restrict__ gamma,
                                                 const float* __restrict__ beta,
                                                 u16* __restrict__ bnT) {
    const int d = blockIdx.x;
    const int t = threadIdx.x;
    float vals[8];
    float s = 0.f, ss = 0.f;
#pragma unroll
    for (int i = 0; i < 8; ++i) {
        float v = lamT[(long)(i * 256 + t) * 256 + d];
        vals[i] = v;
        s += v;
        ss += v * v;
    }
#pragma unroll
    for (int sh = 32; sh > 0; sh >>= 1) {
        s += __shfl_xor(s, sh, 64);
        ss += __shfl_xor(ss, sh, 64);
    }
    __shared__ float red[8];
    int w = t >> 6;
    if ((t & 63) == 0) {
        red[w] = s;
        red[w + 4] = ss;
    }
    __syncthreads();
    s = red[0] + red[1] + red[2] + red[3];
    ss = red[4] + red[5] + red[6] + red[7];
    float mean = s * (1.f / 2048.f);
    float var = ss * (1.f / 2048.f) - mean * mean;
    float scale = gamma[d] * rsqrtf(var + 1e-5f);
    float shift = beta[d] - mean * scale;
#pragma unroll
    for (int i = 0; i < 8; ++i)
        bnT[(long)(i * 256 + t) * 256 + d] = f2b(vals[i] * scale + shift);
}

// ---------------------------------------------------------------------------
// outb[b][e] = sum_d bq[d] * bnT[b][e][d]   (folded query bias)
// ---------------------------------------------------------------------------
__global__ __launch_bounds__(256) void outb_kernel(const float* __restrict__ bq,
                                                   const u16* __restrict__ bnT,
                                                   float* __restrict__ outb) {
    int b = blockIdx.x, e = threadIdx.x;
    const u16* rowp = bnT + ((long)b * 256 + e) * 256;
    float s = 0.f;
    for (int dd = 0; dd < 256; ++dd) s += bq[dd] * b2f(rowp[dd]);
    outb[b * 256 + e] = s;
}

// ---------------------------------------------------------------------------
extern "C" void kernel_launch(void* const* d_in, const int* in_sizes, int n_in,
                              void* d_out, int out_size, void* d_ws, size_t ws_size,
                              hipStream_t stream) {
    const float* feat = (const float*)d_in[0];   // (8,8192,256) f32
    const float* W_qk = (const float*)d_in[1];   // (2,256,256) f32
    const float* b_qk = (const float*)d_in[2];   // (2,256) f32
    const float* W_v = (const float*)d_in[3];    // (256,256) f32
    const float* b_v = (const float*)d_in[4];    // (256,) f32
    const float* gamma = (const float*)d_in[5];  // (256,) f32
    const float* beta = (const float*)d_in[6];   // (256,) f32
    float* out = (float*)d_out;                  // (8,8192,256) f32

    char* ws = (char*)d_ws;
    u16* KT = (u16*)(ws);                        // tiled raw K, 33,554,432 B
    u16* VT = (u16*)(ws + 33554432);             // tiled V,     33,554,432 B
    u16* WkT = (u16*)(ws + 67108864);            // 131072 B
    u16* WvT = (u16*)(ws + 67239936);            // 131072 B
    u16* Wqb = (u16*)(ws + 67371008);            // 131072 B
    float* partial = (float*)(ws + 67502080);    // 2,097,152 B (m,s per chunk)
    float* ctab = (float*)(ws + 69599232);       // 8,192 B
    const size_t base = 69607424;
    float* lamP = (float*)(ws + base);           // S * 2,097,152 B
    size_t avail = (ws_size > base) ? ws_size - base : 0;
    int S = (avail >= 8u * 2097152u) ? 8
          : (avail >= 4u * 2097152u) ? 4 : 2;
    // post-lam buffers alias the dead K region (only written after gemm_lam):
    float* lamT = (float*)ws;                    // 2,097,152 B
    u16* bnT = (u16*)(ws + 2097152);             // 1,048,576 B
    u16* WfoldT = (u16*)(ws + 3145728);          // 1,048,576 B
    float* outb = (float*)(ws + 4194304);        // 8,192 B

    // 1. weight prep
    prep_w<<<768, 256, 0, stream>>>(W_qk, W_v, WkT, WvT, Wqb);
    // 2. fused K/V projection -> tiled layout + softmax partials
    gemm_kv<<<1024, 512, 0, stream>>>(feat, WkT, WvT, b_qk + 256, b_v, KT, VT,
                                      partial);
    // 3. combine partials -> c[b][d]  (parallel)
    stats2<<<dim3(8, 8), 256, 0, stream>>>(partial, ctab);
    // 4. lam partials, full coverage (P computed on the fly) + reduce
    gemm_lam<<<dim3(64, S), 256, 0, stream>>>(VT, KT, ctab, lamP, 8192 / (S * 32));
    reduce_lam<<<512, 256, 0, stream>>>(lamP, lamT, S);
    // 5. BN -> bn^T bf16
    bn_kernel<<<256, 256, 0, stream>>>(lamT, gamma, beta, bnT);
    // 6. folded query bias
    outb_kernel<<<8, 256, 0, stream>>>(b_qk, bnT, outb);
    // 7. Wfold^T = bn^T @ Wq^T
    gemm_fold<<<dim3(32, 4), 256, 0, stream>>>(bnT, Wqb, WfoldT);
    // 8. out = X @ Wfold (+outb)
    gemm_out<<<1024, 256, 0, stream>>>(feat, WfoldT, outb, out);
}